// Round 9
// baseline (4091.416 us; speedup 1.0000x reference)
//
#include <hip/hip_runtime.h>
#include <math.h>

#define TT 128
#define ZD 2048
#define IFC 471
#define EPSF 1e-6f
#define MST 66      // M LDS row stride (66 ≡ 2 mod 32)
#define LST 130     // link LDS row stride (130 ≡ 2 mod 32)
#define NBLK 256
#define UHT 24640   // per-t stride of Uh: 32*768 + 64 guard floats
#define VHT 15424   // per-t stride of Vh: 32*480 + 64 guard floats

// flags: one per 64B cacheline (FSP=16 uints). Per group 64 slots:
// [0..27]=FH (col h arrivals) [28..55]=FV (col v arrivals) [56..59]=FR (state reads)
#define FSP 16
#define NFLAGS 8192   // 8 groups * 64 slots * 16 uints = 32KB

#define D4(a,b) ((a).x*(b).x + (a).y*(b).y + (a).z*(b).z + (a).w*(b).w)

__device__ __forceinline__ float sig_(float x){ return 1.f/(1.f+expf(-x)); }
__device__ __forceinline__ float sp_(float x){ return fmaxf(x,0.f)+log1pf(expf(-fabsf(x))); }

// -------- agent-scope (write-through) publishes: correct on ANY placement --
__device__ __forceinline__ void st1(float* p, float v){
  unsigned u; __builtin_memcpy(&u,&v,4);
  __hip_atomic_store((unsigned*)p, u, __ATOMIC_RELAXED, __HIP_MEMORY_SCOPE_AGENT);
}
__device__ __forceinline__ void st2(float* p, float2 v){
  unsigned long long u; __builtin_memcpy(&u,&v,8);
  __hip_atomic_store((unsigned long long*)p, u, __ATOMIC_RELAXED, __HIP_MEMORY_SCOPE_AGENT);
}

// -------- dataflow sync: single-writer flags, plain agent store of generation.
__device__ __forceinline__ void arrive(unsigned* f, unsigned gen){
  __syncthreads();   // drains vmcnt(0): payload stores coherent before flag store
  if (threadIdx.x == 0)
    __hip_atomic_store(f, gen, __ATOMIC_RELAXED, __HIP_MEMORY_SCOPE_AGENT);
}
// per-thread spin (no barrier inside): caller gates its OWN payload load on
// the producing block's flag; a following __syncthreads orders the LDS stores.
__device__ __forceinline__ void spin1(const unsigned* p, unsigned gen){
  if (__hip_atomic_load(p, __ATOMIC_RELAXED, __HIP_MEMORY_SCOPE_AGENT) >= gen) return;
  int spins = 0;
  while (spins < 64){
    if (__hip_atomic_load(p, __ATOMIC_RELAXED, __HIP_MEMORY_SCOPE_AGENT) >= gen) return;
    __builtin_amdgcn_s_sleep(1); ++spins;
  }
  while (__hip_atomic_load(p, __ATOMIC_RELAXED, __HIP_MEMORY_SCOPE_AGENT) < gen)
    __builtin_amdgcn_s_sleep(2);
}

__device__ __forceinline__ unsigned bf16rne(float f){
  unsigned u; __builtin_memcpy(&u,&f,4);
  return (u + 0x7fffu + ((u>>16)&1u)) >> 16;
}
__device__ __forceinline__ float bflo(unsigned w){
  unsigned u = w << 16; float f; __builtin_memcpy(&f,&u,4); return f;
}
__device__ __forceinline__ float bfhi(unsigned w){
  unsigned u = w & 0xffff0000u; float f; __builtin_memcpy(&f,&u,4); return f;
}

// ---------------- GEMM #1: C[M,N] = A[M,K] @ B[K,N] + bias[N]
__global__ __launch_bounds__(256) void gemm_bias(
    const float* __restrict__ A, const float* __restrict__ B,
    const float* __restrict__ bias, float* __restrict__ C,
    int Nc, int K)
{
  __shared__ float As[16][68];
  __shared__ float Bs[16][68];
  const int tid = threadIdx.x;
  const int bx = blockIdx.x, by = blockIdx.y;
  const int tx = tid & 15, ty = tid >> 4;
  const int am = tid >> 2, ak = (tid & 3) * 4;
  const int bk = tid >> 4, bn = (tid & 15) * 4;
  float acc[4][4] = {};
  const float* Ap = A + (size_t)(by*64+am)*K + ak;
  const float* Bp = B + (size_t)bk*Nc + bx*64 + bn;
  for (int k0 = 0; k0 < K; k0 += 16) {
    float4 av = *(const float4*)Ap; Ap += 16;
    float4 bv = *(const float4*)Bp; Bp += (size_t)16*Nc;
    As[ak+0][am]=av.x; As[ak+1][am]=av.y; As[ak+2][am]=av.z; As[ak+3][am]=av.w;
    *(float4*)&Bs[bk][bn] = bv;
    __syncthreads();
#pragma unroll
    for (int kk = 0; kk < 16; ++kk) {
      float4 a4 = *(const float4*)&As[kk][ty*4];
      float4 b4 = *(const float4*)&Bs[kk][tx*4];
      acc[0][0]+=a4.x*b4.x; acc[0][1]+=a4.x*b4.y; acc[0][2]+=a4.x*b4.z; acc[0][3]+=a4.x*b4.w;
      acc[1][0]+=a4.y*b4.x; acc[1][1]+=a4.y*b4.y; acc[1][2]+=a4.y*b4.z; acc[1][3]+=a4.y*b4.w;
      acc[2][0]+=a4.z*b4.x; acc[2][1]+=a4.z*b4.y; acc[2][2]+=a4.z*b4.z; acc[2][3]+=a4.z*b4.w;
      acc[3][0]+=a4.w*b4.x; acc[3][1]+=a4.w*b4.y; acc[3][2]+=a4.w*b4.z; acc[3][3]+=a4.w*b4.w;
    }
    __syncthreads();
  }
  float4 bb = *(const float4*)(bias + bx*64 + tx*4);
#pragma unroll
  for (int i = 0; i < 4; ++i) {
    float4 o;
    o.x = acc[i][0]+bb.x; o.y = acc[i][1]+bb.y; o.z = acc[i][2]+bb.z; o.w = acc[i][3]+bb.w;
    *(float4*)(C + (size_t)(by*64+ty*4+i)*Nc + bx*64 + tx*4) = o;
  }
}

// ---------------- GEMM #2 (output): A rows live in Uh[t][e] layout.
__global__ __launch_bounds__(256) void gemm_out(
    const float* __restrict__ A, const float* __restrict__ B,
    const float* __restrict__ bias, float* __restrict__ C)
{
  __shared__ float As[16][68];
  __shared__ float Bs[16][68];
  const int tid = threadIdx.x;
  const int bx = blockIdx.x, by = blockIdx.y;
  const int tx = tid & 15, ty = tid >> 4;
  const int am = tid >> 2, ak = (tid & 3) * 4;
  const int bk = tid >> 4, bn = (tid & 15) * 4;
  float acc[4][4] = {};
  const int arow = by*64 + am;
  const float* Ap = A + (size_t)(arow >> 5)*UHT + (size_t)(arow & 31)*768 + ak;
  const float* Bp = B + (size_t)bk*512 + bx*64 + bn;
  for (int k0 = 0; k0 < 768; k0 += 16) {
    float4 av = *(const float4*)Ap; Ap += 16;
    float4 bv = *(const float4*)Bp; Bp += (size_t)16*512;
    As[ak+0][am]=av.x; As[ak+1][am]=av.y; As[ak+2][am]=av.z; As[ak+3][am]=av.w;
    *(float4*)&Bs[bk][bn] = bv;
    __syncthreads();
#pragma unroll
    for (int kk = 0; kk < 16; ++kk) {
      float4 a4 = *(const float4*)&As[kk][ty*4];
      float4 b4 = *(const float4*)&Bs[kk][tx*4];
      acc[0][0]+=a4.x*b4.x; acc[0][1]+=a4.x*b4.y; acc[0][2]+=a4.x*b4.z; acc[0][3]+=a4.x*b4.w;
      acc[1][0]+=a4.y*b4.x; acc[1][1]+=a4.y*b4.y; acc[1][2]+=a4.y*b4.z; acc[1][3]+=a4.y*b4.w;
      acc[2][0]+=a4.z*b4.x; acc[2][1]+=a4.z*b4.y; acc[2][2]+=a4.z*b4.z; acc[2][3]+=a4.z*b4.w;
      acc[3][0]+=a4.w*b4.x; acc[3][1]+=a4.w*b4.y; acc[3][2]+=a4.w*b4.z; acc[3][3]+=a4.w*b4.w;
    }
    __syncthreads();
  }
  float4 bb = *(const float4*)(bias + bx*64 + tx*4);
#pragma unroll
  for (int i = 0; i < 4; ++i) {
    int row = by*64 + ty*4 + i;
    int crow = (row & 31)*128 + (row >> 5);   // (e,t) -> e*128+t
    float4 o;
    o.x = acc[i][0]+bb.x; o.y = acc[i][1]+bb.y; o.z = acc[i][2]+bb.z; o.w = acc[i][3]+bb.w;
    *(float4*)(C + (size_t)crow*512 + bx*64 + tx*4) = o;
  }
}

// ---------------- state-block LDS layout (floats)
#define SL_L    0          // 128*130 = 16640
#define SL_M    16640      // 128*66  = 8448
#define SL_V    25088      // 480
#define SL_WR   25568      // 512
#define SL_FW   26080      // 512
#define SL_BW   26592      // 512
#define SL_CR   27104      // 512
#define SL_USG  27616      // 128
#define SL_PRC  27744      // 128
#define SL_WW   27872      // 128
#define SL_SU   28000      // 128
#define SL_CPX  28128      // 128
#define SL_MN   28256      // 128
#define SL_SW   28384      // 128
#define SL_CW   28512      // 128
#define SL_RNK  28640      // 128
#define SL_MSC  28768      // 64
#define SL_ER   28832      // 64
#define SL_WV   28896      // 64
#define SL_TOT  28960

// ---------------- col-block LDS layout
// Wzu: uint[76][390]  (bf16-pair z-weights; even stride, aligned uint2 reads)
// Wiu: uint[17][262]
// us:  float[4][772]  (reads 0..255, h 256..767)  [base 34096 ≡ 0 mod 4: 16B aligned]
// zh:  float[4][76] ; cst: float[76]
#define CWI_U  29640
#define CUS_F  34096
#define CZH_F  37184
#define CCS_F  37488
#define CTOT_F 37564   // 150256 B

__global__ void init_flags(unsigned* flags) {
  int idx = blockIdx.x*1024 + threadIdx.x;
  if (idx < NFLAGS)
    __hip_atomic_store(&flags[idx], 0u, __ATOMIC_RELAXED, __HIP_MEMORY_SCOPE_AGENT);
}

__global__ __launch_bounds__(1024) void dnc_coop(
    const float* __restrict__ Xproj, const float* __restrict__ Wx,
    const float* __restrict__ Wh, const float* __restrict__ Wif,
    const float* __restrict__ bif,
    float* __restrict__ Uh, float* __restrict__ Vh,
    unsigned* __restrict__ flags)
{
  const int blk = blockIdx.x, tid = threadIdx.x;
  extern __shared__ float sm[];
  const int g = blk & 7;          // group (heuristically = XCD via round-robin)
  const int role = blk >> 3;      // 0..31 within group
  unsigned* FHg = flags + (size_t)g*64*FSP;        // slots 0..27
  unsigned* FVg = FHg + 28*FSP;                    // slots 28..55
  unsigned* FRg = FHg + 56*FSP;                    // slots 56..59

  if (role < 4) {
    // ================= STATE BLOCK (example eg) =================
    const int eg = g*4 + role;
    float* L   = sm + SL_L;   float* Ms  = sm + SL_M;
    float* v   = sm + SL_V;   float* wr  = sm + SL_WR;
    float* fw  = sm + SL_FW;  float* bw  = sm + SL_BW;
    float* cr  = sm + SL_CR;  float* usg = sm + SL_USG;
    float* prc = sm + SL_PRC; float* ww  = sm + SL_WW;
    float* su  = sm + SL_SU;  float* cpx = sm + SL_CPX;
    float* Mn  = sm + SL_MN;  float* swv = sm + SL_SW;
    float* cw  = sm + SL_CW;  int*   rnk = (int*)(sm + SL_RNK);
    float* msc = sm + SL_MSC; float* er_ = sm + SL_ER; float* wv_ = sm + SL_WV;

    // col block owning v-column tid:  v0(c)=floor(471c/28)  =>  c=floor((28*tid+27)/471)
    const int vown = (tid < IFC) ? (28*tid + 27)/471 : 0;

    for (int i = tid; i < SL_TOT; i += 1024) sm[i] = 0.f;
    __syncthreads();

    for (int t = 0; t < TT; ++t) {
      // hop 1 pipelined: each thread gates its OWN v-column on the owning
      // col's FV flag, overlapping straggler-wait with payload fetch.
      if (tid < IFC) {
        spin1(&FVg[vown*FSP], t+1);
        v[tid] = Vh[(size_t)t*VHT + eg*480 + tid];
      }
      __syncthreads();
      // B
      if (tid < 128) {
        float ret = 1.f;
#pragma unroll
        for (int r = 0; r < 4; ++r) { float fr = sig_(v[453+r]); ret *= 1.f - fr*wr[r*128+tid]; }
        float u = usg[tid], w_ = ww[tid];
        usg[tid] = (u + w_ - u*w_) * ret;
      } else if (tid < 256) {
        int n = tid - 128; float nk = 0.f, dot = 0.f;
#pragma unroll
        for (int w = 0; w < 64; w += 2) {
          float2 k2 = *(float2*)&v[260+w];
          float2 m2 = *(float2*)&Ms[n*MST+w];
          nk += k2.x*k2.x + k2.y*k2.y; dot += m2.x*k2.x + m2.y*k2.y;
        }
        float beta = 1.f + sp_(v[324]);
        swv[n] = beta * dot / ((Mn[n]+EPSF)*(sqrtf(nk)+EPSF));
      } else if (tid < 260) {
        int r = tid - 256; float s = 0.f;
#pragma unroll
        for (int w = 0; w < 64; w += 4) { float4 k4 = *(float4*)&v[r*64+w]; s += D4(k4,k4); }
        msc[1+r] = sqrtf(s);
      } else if (tid == 260) {
        for (int r = 0; r < 4; ++r) {
          float a0 = v[459+r*3], a1 = v[459+r*3+1], a2 = v[459+r*3+2];
          float mx = fmaxf(a0, fmaxf(a1, a2));
          float e0 = expf(a0-mx), e1 = expf(a1-mx), e2 = expf(a2-mx);
          float dn = e0+e1+e2;
          msc[8+r*3] = e0/dn; msc[8+r*3+1] = e1/dn; msc[8+r*3+2] = e2/dn;
        }
      } else if (tid >= 640 && tid < 704) { int w = tid-640; er_[w] = sig_(v[325+w]); }
      else if (tid >= 704 && tid < 768) { int w = tid-704; wv_[w] = v[389+w]; }
      __syncthreads();
      // C — rank (vectorized broadcast reads)
      if (tid < 128) {
        float ui = usg[tid]; int rk = 0;
#pragma unroll
        for (int j = 0; j < 128; j += 4) {
          float4 u4 = *(float4*)&usg[j];
          rk += (u4.x < ui || (u4.x == ui && (j+0) < tid)) ? 1 : 0;
          rk += (u4.y < ui || (u4.y == ui && (j+1) < tid)) ? 1 : 0;
          rk += (u4.z < ui || (u4.z == ui && (j+2) < tid)) ? 1 : 0;
          rk += (u4.w < ui || (u4.w == ui && (j+3) < tid)) ? 1 : 0;
        }
        rnk[tid] = rk; su[rk] = ui;
      } else if (tid < 192) {
        int l = tid - 128;
        float s1 = swv[l], s2 = swv[l+64];
        float m = fmaxf(s1, s2);
#pragma unroll
        for (int o = 32; o > 0; o >>= 1) m = fmaxf(m, __shfl_xor(m, o));
        float e1 = expf(s1-m), e2 = expf(s2-m);
        float dn = e1 + e2;
#pragma unroll
        for (int o = 32; o > 0; o >>= 1) dn += __shfl_xor(dn, o);
        cw[l] = e1/dn; cw[l+64] = e2/dn;
      }
      __syncthreads();
      // D' cumprod + ww (+fused ww-sum -> msc[0])
      if (tid < 64) {
        float a0 = su[2*tid], a1 = su[2*tid+1];
        float p = a0*a1, sc = p;
#pragma unroll
        for (int off = 1; off < 64; off <<= 1) {
          float o = __shfl_up(sc, off);
          if ((int)tid >= off) sc *= o;
        }
        float ex = __shfl_up(sc, 1);
        if (tid == 0) ex = 1.f;
        cpx[2*tid] = ex;
        cpx[2*tid+1] = ex*a0;
        float ag = sig_(v[457]), wg = sig_(v[458]);
        float wwa[2];
#pragma unroll
        for (int q = 0; q < 2; ++q) {
          int n = 2*tid + q;
          float a_i = (1.f - usg[n]) * cpx[rnk[n]];
          wwa[q] = wg * (ag*a_i + (1.f-ag)*cw[n]);
          ww[n] = wwa[q];
        }
        float s = wwa[0] + wwa[1];
#pragma unroll
        for (int o = 32; o > 0; o >>= 1) s += __shfl_xor(s, o);
        if (tid == 0) msc[0] = s;
      }
      __syncthreads();
      // F (+fused Mn of post-write M from register values)
      {
        int n = tid >> 3, q = tid & 7;
        float wwn = ww[n];
        int w8 = q*8;
        float sq = 0.f;
#pragma unroll
        for (int gq = 0; gq < 4; ++gq) {
          int w = w8 + gq*2;
          float2 m = *(float2*)&Ms[n*MST+w];
          float2 e2 = *(float2*)&er_[w];
          float2 v2 = *(float2*)&wv_[w];
          m.x = m.x*(1.f - wwn*e2.x) + wwn*v2.x;
          m.y = m.y*(1.f - wwn*e2.y) + wwn*v2.y;
          *(float2*)&Ms[n*MST+w] = m;
          sq += m.x*m.x + m.y*m.y;
        }
        sq += __shfl_xor(sq,1); sq += __shfl_xor(sq,2); sq += __shfl_xor(sq,4);
        if (q == 0) Mn[n] = sqrtf(sq);
        int j16 = q*16;
#pragma unroll
        for (int gq = 0; gq < 8; ++gq) {
          int j = j16 + gq*2;
          float2 lv = *(float2*)&L[n*LST + j];
          float2 p2 = *(float2*)&prc[j];
          float2 w2 = *(float2*)&ww[j];
          lv.x = (1.f - wwn - w2.x)*lv.x + wwn*p2.x;
          lv.y = (1.f - wwn - w2.y)*lv.y + wwn*p2.y;
          int d = n - j;
          if (d == 0) lv.x = 0.f;
          if (d == 1) lv.y = 0.f;
          *(float2*)&L[n*LST + j] = lv;
        }
      }
      __syncthreads();
      // H'
      if (tid < 256) {
        int half = tid >> 7, t2 = tid & 127;
        int i0 = (t2 >> 2) * 4, sg = t2 & 3;
        float4 av[4] = {{0,0,0,0},{0,0,0,0},{0,0,0,0},{0,0,0,0}};
        if (half == 0) {
#pragma unroll
          for (int m = 0; m < 8; ++m) {
            int j = sg*4 + m*16;
            float4 w0 = *(float4*)&wr[0*128+j];
            float4 w1 = *(float4*)&wr[1*128+j];
            float4 w2 = *(float4*)&wr[2*128+j];
            float4 w3 = *(float4*)&wr[3*128+j];
#pragma unroll
            for (int k = 0; k < 4; ++k) {
              float2 la = *(float2*)&L[(i0+k)*LST+j];
              float2 lb = *(float2*)&L[(i0+k)*LST+j+2];
              float dv0 = la.x*w0.x + la.y*w0.y + lb.x*w0.z + lb.y*w0.w;
              float dv1 = la.x*w1.x + la.y*w1.y + lb.x*w1.z + lb.y*w1.w;
              float dv2 = la.x*w2.x + la.y*w2.y + lb.x*w2.z + lb.y*w2.w;
              float dv3 = la.x*w3.x + la.y*w3.y + lb.x*w3.z + lb.y*w3.w;
              if (k == 0){ av[0].x+=dv0; av[1].x+=dv1; av[2].x+=dv2; av[3].x+=dv3; }
              if (k == 1){ av[0].y+=dv0; av[1].y+=dv1; av[2].y+=dv2; av[3].y+=dv3; }
              if (k == 2){ av[0].z+=dv0; av[1].z+=dv1; av[2].z+=dv2; av[3].z+=dv3; }
              if (k == 3){ av[0].w+=dv0; av[1].w+=dv1; av[2].w+=dv2; av[3].w+=dv3; }
            }
          }
        } else {
#pragma unroll
          for (int m = 0; m < 32; ++m) {
            int j = sg + m*4;
            float2 la = *(float2*)&L[j*LST + i0];
            float2 lb = *(float2*)&L[j*LST + i0 + 2];
            float w0 = wr[j], w1 = wr[128+j], w2 = wr[256+j], w3 = wr[384+j];
            av[0].x+=w0*la.x; av[0].y+=w0*la.y; av[0].z+=w0*lb.x; av[0].w+=w0*lb.y;
            av[1].x+=w1*la.x; av[1].y+=w1*la.y; av[1].z+=w1*lb.x; av[1].w+=w1*lb.y;
            av[2].x+=w2*la.x; av[2].y+=w2*la.y; av[2].z+=w2*lb.x; av[2].w+=w2*lb.y;
            av[3].x+=w3*la.x; av[3].y+=w3*la.y; av[3].z+=w3*lb.x; av[3].w+=w3*lb.y;
          }
        }
#pragma unroll
        for (int r = 0; r < 4; ++r) {
          av[r].x += __shfl_xor(av[r].x,1); av[r].x += __shfl_xor(av[r].x,2);
          av[r].y += __shfl_xor(av[r].y,1); av[r].y += __shfl_xor(av[r].y,2);
          av[r].z += __shfl_xor(av[r].z,1); av[r].z += __shfl_xor(av[r].z,2);
          av[r].w += __shfl_xor(av[r].w,1); av[r].w += __shfl_xor(av[r].w,2);
        }
        if (sg == 0) {
          float* dst = half ? bw : fw;
#pragma unroll
          for (int r = 0; r < 4; ++r) {
            dst[r*128 + i0+0] = av[r].x; dst[r*128 + i0+1] = av[r].y;
            dst[r*128 + i0+2] = av[r].z; dst[r*128 + i0+3] = av[r].w;
          }
        }
      } else if (tid < 384) {
        int n = tid - 256;
        prc[n] = (1.f - msc[0])*prc[n] + ww[n];
      } else if (tid >= 512) {
        int r = (tid >> 7) & 3, n = tid & 127;
        float dot = 0.f;
#pragma unroll
        for (int w = 0; w < 64; w += 2) {
          float2 m2 = *(float2*)&Ms[n*MST+w];
          float2 k2 = *(float2*)&v[r*64+w];
          dot += m2.x*k2.x + m2.y*k2.y;
        }
        float beta = 1.f + sp_(v[256+r]);
        cr[r*128+n] = beta * dot / ((Mn[n]+EPSF)*(msc[1+r]+EPSF));
      }
      __syncthreads();
      // J'
      if (tid < 256) {
        int r = tid >> 6, l = tid & 63;
        float s1 = cr[r*128+l], s2 = cr[r*128+l+64];
        float m = fmaxf(s1, s2);
#pragma unroll
        for (int o = 32; o > 0; o >>= 1) m = fmaxf(m, __shfl_xor(m, o));
        float e1 = expf(s1-m), e2 = expf(s2-m);
        float dn = e1 + e2;
#pragma unroll
        for (int o = 32; o > 0; o >>= 1) dn += __shfl_xor(dn, o);
        float m0 = msc[8+r*3], m1 = msc[8+r*3+1], m2 = msc[8+r*3+2];
        wr[r*128+l]    = m0*bw[r*128+l]    + m1*(e1/dn) + m2*fw[r*128+l];
        wr[r*128+l+64] = m0*bw[r*128+l+64] + m1*(e2/dn) + m2*fw[r*128+l+64];
      }
      __syncthreads();
      // L: reads publish
      if (tid < 512) {
        int r = tid >> 7, t2 = tid & 127;
        int w0 = (t2 >> 3) * 4, ns = t2 & 7;
        float4 a = {0,0,0,0};
#pragma unroll
        for (int m = 0; m < 16; ++m) {
          int n = ns + m*8;
          float2 ma = *(float2*)&Ms[n*MST + w0];
          float2 mb = *(float2*)&Ms[n*MST + w0 + 2];
          float wv = wr[r*128 + n];
          a.x += wv*ma.x; a.y += wv*ma.y; a.z += wv*mb.x; a.w += wv*mb.y;
        }
        a.x += __shfl_xor(a.x,1); a.x += __shfl_xor(a.x,2); a.x += __shfl_xor(a.x,4);
        a.y += __shfl_xor(a.y,1); a.y += __shfl_xor(a.y,2); a.y += __shfl_xor(a.y,4);
        a.z += __shfl_xor(a.z,1); a.z += __shfl_xor(a.z,2); a.z += __shfl_xor(a.z,4);
        a.w += __shfl_xor(a.w,1); a.w += __shfl_xor(a.w,2); a.w += __shfl_xor(a.w,4);
        if (ns == 0) {
          int o = r*64 + w0;
          float2 lo = {a.x, a.y}, hi = {a.z, a.w};
          st2(&Uh[(size_t)t*UHT + eg*768 + o], lo);
          st2(&Uh[(size_t)t*UHT + eg*768 + o + 2], hi);
        }
      }
      arrive(&FRg[role*FSP], t+1);   // reads(t) published
    }
  } else {
    // ======== COL BLOCK c: h-dims [d0,d1) x 4 gate quadrants + v-cols [v0,v1) ====
    const int c = role - 4;                       // 0..27
    const int egB = g*4;                          // group's first example
    const int d0 = (512*c)/28, d1 = (512*(c+1))/28, Dd = d1-d0, NJ = 4*Dd;
    const int v0 = (471*c)/28, v1 = (471*(c+1))/28, JV = v1-v0;
    unsigned* Wzu = (unsigned*)sm;                // [76][390]
    unsigned* Wiu = (unsigned*)sm + CWI_U;        // [17][262]
    float* us  = sm + CUS_F;                      // [4][772]  16B-aligned base
    float* zh  = sm + CZH_F;                      // [4][76]
    float* cst = sm + CCS_F;                      // [76]

    // h-stage chunk ownership: dim d owned by col floor((28d+27)/512)
    const int hf4 = (tid & 127) * 4;
    const int hc0 = (28*hf4 + 27) >> 9;
    const int hc1 = (28*(hf4+3) + 27) >> 9;

    // ---- one-time: pack weights to bf16 pairs in LDS
    for (int idx = tid; idx < NJ*384; idx += 1024) {
      int j = idx/384, p = idx - j*384, k = 2*p;
      int q = j/Dd, di = j - q*Dd, gc = q*512 + d0 + di;
      float w0 = (k < 256) ? Wx[(size_t)(512+k)*ZD + gc] : Wh[(size_t)(k-256)*ZD + gc];
      float w1 = (k+1 < 256) ? Wx[(size_t)(513+k)*ZD + gc] : Wh[(size_t)(k-255)*ZD + gc];
      Wzu[j*390 + p] = bf16rne(w0) | (bf16rne(w1) << 16);
    }
    for (int idx = tid; idx < JV*256; idx += 1024) {
      int j = idx/256, p = idx - j*256, k = 2*p, gc = v0 + j;
      float w0 = Wif[(size_t)k*IFC + gc];
      float w1 = Wif[(size_t)(k+1)*IFC + gc];
      Wiu[j*262 + p] = bf16rne(w0) | (bf16rne(w1) << 16);
    }
    if (tid < 76) cst[tid] = 0.f;
    // bootstrap z(0) = Xproj(0)
    if (tid < 4*NJ) {
      int e = tid/NJ, j = tid - e*NJ;
      int q = j/Dd, di = j - q*Dd, gc = q*512 + d0 + di;
      zh[e*76 + j] = Xproj[((size_t)(egB+e)*TT + 0)*ZD + gc];
    }
    __syncthreads();
    if (tid < 4*Dd) {
      int e = tid/Dd, di = tid - e*Dd;
      float zi = zh[e*76 + di], zg = zh[e*76 + 2*Dd + di], zo = zh[e*76 + 3*Dd + di];
      float cn = sig_(zi)*tanhf(zg);
      float hn = sig_(zo)*tanhf(cn);
      cst[tid] = cn;
      st1(&Uh[(size_t)0*UHT + (egB + e)*768 + 256 + d0 + di], hn);
    }
    arrive(&FHg[c*FSP], 1);   // h(0) published

    for (int t = 0; t < TT; ++t) {
      // prefetch Xproj(t+1) into registers BEFORE the flag spins
      float xpre = 0.f; int pe = 0, pj = 0;
      if (t+1 < TT && tid < 4*NJ) {
        pe = tid/NJ; pj = tid - pe*NJ;
        int q = pj/Dd, di = pj - q*Dd, gc = q*512 + d0 + di;
        xpre = Xproj[((size_t)(egB+pe)*TT + t+1)*ZD + gc];
      }
      // hop 3 pipelined: each staging thread gates its OWN 4-dim chunk on
      // the owning col(s)' FH flags — no all-28 rendezvous on this path.
      if (tid < 512) {
        int e = tid >> 7;
        spin1(&FHg[hc0*FSP], t+1);
        if (hc1 != hc0) spin1(&FHg[hc1*FSP], t+1);
        *(float4*)&us[e*772 + 256 + hf4] =
            *(const float4*)&Uh[(size_t)t*UHT + (egB+e)*768 + 256 + hf4];
      }
      // zh(t+1) init from prefetched Xproj
      if (t+1 < TT && tid < 4*NJ) {
        zh[pe*76 + pj] = xpre;
      }
      __syncthreads();
      // v-gemm: 4e x JV cols, K=512, 8-way k-split, b64 weights + b128 activations
      if (tid < 544) {
        int g8 = tid >> 3, ks = tid & 7;
        int e = g8/17, j = g8 - e*17;
        if (j < JV) {
          float acc = 0.f;
#pragma unroll 4
          for (int m = 0; m < 16; ++m) {
            int p = m*16 + ks*2;
            float4 hv = *(const float4*)&us[e*772 + 256 + 2*p];
            uint2 wu = *(const uint2*)&Wiu[j*262 + p];
            acc += hv.x*bflo(wu.x) + hv.y*bfhi(wu.x)
                 + hv.z*bflo(wu.y) + hv.w*bfhi(wu.y);
          }
          acc += __shfl_xor(acc,1); acc += __shfl_xor(acc,2); acc += __shfl_xor(acc,4);
          if (ks == 0) {
            int col = v0 + j;
            st1(&Vh[(size_t)t*VHT + (egB+e)*480 + col], bif[col] + acc);
          }
        }
      }
      arrive(&FVg[c*FSP], t+1);   // v(t) published
      if (t+1 < TT) {
        // hop 2 pipelined: z-Wh gemm (tid<608) runs CONCURRENTLY with
        // FR-gated reads staging (tid 640..895); one barrier joins them.
        if (tid < 608) {
          int q2 = tid >> 1, ks = tid & 1;
          int e = q2/76, j = q2 - e*76;
          if (j < NJ) {
            float acc = 0.f;
#pragma unroll 4
            for (int m = 0; m < 64; ++m) {
              int p = 128 + m*4 + ks*2;
              float4 hv = *(const float4*)&us[e*772 + 2*p];   // 2p>=256 -> h region
              uint2 wu = *(const uint2*)&Wzu[j*390 + p];
              acc += hv.x*bflo(wu.x) + hv.y*bfhi(wu.x)
                   + hv.z*bflo(wu.y) + hv.w*bfhi(wu.y);
            }
            acc += __shfl_xor(acc,1);
            if (ks == 0) zh[e*76 + j] += acc;
          }
        } else if (tid >= 640 && tid < 896) {
          int e2 = (tid - 640) >> 6, f4b = ((tid - 640) & 63) * 4;
          spin1(&FRg[e2*FSP], t+1);
          *(float4*)&us[e2*772 + f4b] =
              *(const float4*)&Uh[(size_t)t*UHT + (egB+e2)*768 + f4b];
        }
        __syncthreads();
        // z += reads(t) @ WxR-part (K=256) — b64 weights + b128 activations
        if (tid < 608) {
          int q2 = tid >> 1, ks = tid & 1;
          int e = q2/76, j = q2 - e*76;
          if (j < NJ) {
            float acc = 0.f;
#pragma unroll 4
            for (int m = 0; m < 32; ++m) {
              int p = m*4 + ks*2;
              float4 rv = *(const float4*)&us[e*772 + 2*p];
              uint2 wu = *(const uint2*)&Wzu[j*390 + p];
              acc += rv.x*bflo(wu.x) + rv.y*bfhi(wu.x)
                   + rv.z*bflo(wu.y) + rv.w*bfhi(wu.y);
            }
            acc += __shfl_xor(acc,1);
            if (ks == 0) zh[e*76 + j] += acc;
          }
        }
        __syncthreads();
        // gates -> h(t+1), publish
        if (tid < 4*Dd) {
          int e = tid/Dd, di = tid - e*Dd;
          float zi = zh[e*76 + di],      zf = zh[e*76 + Dd + di];
          float zg = zh[e*76 + 2*Dd+di], zo = zh[e*76 + 3*Dd + di];
          float cn = sig_(zf)*cst[tid] + sig_(zi)*tanhf(zg);
          float hn = sig_(zo)*tanhf(cn);
          cst[tid] = cn;
          st1(&Uh[(size_t)(t+1)*UHT + (egB+e)*768 + 256 + d0 + di], hn);
        }
        arrive(&FHg[c*FSP], t+2);   // h(t+1) published
      }
    }
  }
}

extern "C" void kernel_launch(void* const* d_in, const int* in_sizes, int n_in,
                              void* d_out, int out_size, void* d_ws, size_t ws_size,
                              hipStream_t stream) {
  const float* x   = (const float*)d_in[0];
  const float* Wx  = (const float*)d_in[1];
  const float* Wh  = (const float*)d_in[2];
  const float* bl  = (const float*)d_in[3];
  const float* Wif = (const float*)d_in[4];
  const float* bif = (const float*)d_in[5];
  const float* Wo  = (const float*)d_in[6];
  const float* bo  = (const float*)d_in[7];
  float* out = (float*)d_out;

  unsigned* fl = (unsigned*)d_ws;                   // 8192 uints = 32KB (cacheline-spaced flags)
  float* Xp = (float*)(fl + NFLAGS);                // 4096*2048
  float* Uh = Xp + (size_t)4096*2048;               // 128*UHT
  float* Vh = Uh + (size_t)TT*UHT;                  // 128*VHT

  // 1) Xproj = x @ Wx[:512] + b_lstm
  gemm_bias<<<dim3(2048/64, 4096/64), dim3(256), 0, stream>>>(x, Wx, bl, Xp, 2048, 512);

  // 2) flags
  init_flags<<<dim3(8), dim3(1024), 0, stream>>>(fl);

  // 3) XCD-sharded cooperative core: 8 groups x (4 state + 28 col) blocks
  const int smem_bytes = CTOT_F * 4;  // 150256
  (void)hipFuncSetAttribute((const void*)dnc_coop, hipFuncAttributeMaxDynamicSharedMemorySize, smem_bytes);
  void* args[] = { (void*)&Xp, (void*)&Wx, (void*)&Wh, (void*)&Wif, (void*)&bif,
                   (void*)&Uh, (void*)&Vh, (void*)&fl };
  (void)hipLaunchCooperativeKernel((void*)dnc_coop, dim3(NBLK), dim3(1024), args,
                                   (unsigned int)smem_bytes, stream);

  // 4) out = [reads,h] @ W_out + b_out
  gemm_out<<<dim3(512/64, 4096/64), dim3(256), 0, stream>>>(Uh, Wo, bo, out);
}

// Round 10
// 3978.792 us; speedup vs baseline: 1.0283x; 1.0283x over previous
//
#include <hip/hip_runtime.h>
#include <math.h>

#define TT 128
#define ZD 2048
#define IFC 471
#define EPSF 1e-6f
#define MST 66      // M LDS row stride (66 ≡ 2 mod 32)
#define LST 130     // link LDS row stride (130 ≡ 2 mod 32)
#define NBLK 256
#define UHT 24640   // per-t stride of Uh: 32*768 + 64 guard floats
#define VHT 15424   // per-t stride of Vh: 32*480 + 64 guard floats

// flags: one per 64B cacheline (FSP=16 uints). Per group 64 slots:
// [0..27]=FH (col h arrivals) [28..55]=FV (col v arrivals) [56..59]=FR (state reads)
#define FSP 16
#define NFLAGS 8192   // 8 groups * 64 slots * 16 uints = 32KB

#define D4(a,b) ((a).x*(b).x + (a).y*(b).y + (a).z*(b).z + (a).w*(b).w)

__device__ __forceinline__ float sig_(float x){ return 1.f/(1.f+expf(-x)); }
__device__ __forceinline__ float sp_(float x){ return fmaxf(x,0.f)+log1pf(expf(-fabsf(x))); }

// -------- agent-scope (write-through) publishes: correct on ANY placement --
__device__ __forceinline__ void st1(float* p, float v){
  unsigned u; __builtin_memcpy(&u,&v,4);
  __hip_atomic_store((unsigned*)p, u, __ATOMIC_RELAXED, __HIP_MEMORY_SCOPE_AGENT);
}
__device__ __forceinline__ void st2(float* p, float2 v){
  unsigned long long u; __builtin_memcpy(&u,&v,8);
  __hip_atomic_store((unsigned long long*)p, u, __ATOMIC_RELAXED, __HIP_MEMORY_SCOPE_AGENT);
}

// -------- dataflow sync: single-writer flags, plain agent store of generation.
__device__ __forceinline__ void arrive(unsigned* f, unsigned gen){
  __syncthreads();   // drains vmcnt(0): payload stores coherent before flag store
  if (threadIdx.x == 0)
    __hip_atomic_store(f, gen, __ATOMIC_RELAXED, __HIP_MEMORY_SCOPE_AGENT);
}
__device__ __forceinline__ void wait_ge(const unsigned* f, int n, unsigned gen){
  if (threadIdx.x < 64){
    for (int i = threadIdx.x; i < n; i += 64){
      const unsigned* p = f + (size_t)i*FSP;
      if (__hip_atomic_load(p, __ATOMIC_RELAXED, __HIP_MEMORY_SCOPE_AGENT) >= gen) continue;
      int spins = 0; bool done = false;
      while (spins < 64){
        if (__hip_atomic_load(p, __ATOMIC_RELAXED, __HIP_MEMORY_SCOPE_AGENT) >= gen){ done = true; break; }
        __builtin_amdgcn_s_sleep(1); ++spins;
      }
      if (!done){
        while (__hip_atomic_load(p, __ATOMIC_RELAXED, __HIP_MEMORY_SCOPE_AGENT) < gen)
          __builtin_amdgcn_s_sleep(2);
      }
    }
  }
  __syncthreads();
}
// per-wave spin used by dedicated staging waves (cross-wave overlap with compute)
__device__ __forceinline__ void spin1(const unsigned* p, unsigned gen){
  if (__hip_atomic_load(p, __ATOMIC_RELAXED, __HIP_MEMORY_SCOPE_AGENT) >= gen) return;
  int spins = 0;
  while (spins < 64){
    if (__hip_atomic_load(p, __ATOMIC_RELAXED, __HIP_MEMORY_SCOPE_AGENT) >= gen) return;
    __builtin_amdgcn_s_sleep(1); ++spins;
  }
  while (__hip_atomic_load(p, __ATOMIC_RELAXED, __HIP_MEMORY_SCOPE_AGENT) < gen)
    __builtin_amdgcn_s_sleep(2);
}

__device__ __forceinline__ unsigned bf16rne(float f){
  unsigned u; __builtin_memcpy(&u,&f,4);
  return (u + 0x7fffu + ((u>>16)&1u)) >> 16;
}
__device__ __forceinline__ float bflo(unsigned w){
  unsigned u = w << 16; float f; __builtin_memcpy(&f,&u,4); return f;
}
__device__ __forceinline__ float bfhi(unsigned w){
  unsigned u = w & 0xffff0000u; float f; __builtin_memcpy(&f,&u,4); return f;
}

// ---------------- GEMM #1: C[M,N] = A[M,K] @ B[K,N] + bias[N]
__global__ __launch_bounds__(256) void gemm_bias(
    const float* __restrict__ A, const float* __restrict__ B,
    const float* __restrict__ bias, float* __restrict__ C,
    int Nc, int K)
{
  __shared__ float As[16][68];
  __shared__ float Bs[16][68];
  const int tid = threadIdx.x;
  const int bx = blockIdx.x, by = blockIdx.y;
  const int tx = tid & 15, ty = tid >> 4;
  const int am = tid >> 2, ak = (tid & 3) * 4;
  const int bk = tid >> 4, bn = (tid & 15) * 4;
  float acc[4][4] = {};
  const float* Ap = A + (size_t)(by*64+am)*K + ak;
  const float* Bp = B + (size_t)bk*Nc + bx*64 + bn;
  for (int k0 = 0; k0 < K; k0 += 16) {
    float4 av = *(const float4*)Ap; Ap += 16;
    float4 bv = *(const float4*)Bp; Bp += (size_t)16*Nc;
    As[ak+0][am]=av.x; As[ak+1][am]=av.y; As[ak+2][am]=av.z; As[ak+3][am]=av.w;
    *(float4*)&Bs[bk][bn] = bv;
    __syncthreads();
#pragma unroll
    for (int kk = 0; kk < 16; ++kk) {
      float4 a4 = *(const float4*)&As[kk][ty*4];
      float4 b4 = *(const float4*)&Bs[kk][tx*4];
      acc[0][0]+=a4.x*b4.x; acc[0][1]+=a4.x*b4.y; acc[0][2]+=a4.x*b4.z; acc[0][3]+=a4.x*b4.w;
      acc[1][0]+=a4.y*b4.x; acc[1][1]+=a4.y*b4.y; acc[1][2]+=a4.y*b4.z; acc[1][3]+=a4.y*b4.w;
      acc[2][0]+=a4.z*b4.x; acc[2][1]+=a4.z*b4.y; acc[2][2]+=a4.z*b4.z; acc[2][3]+=a4.z*b4.w;
      acc[3][0]+=a4.w*b4.x; acc[3][1]+=a4.w*b4.y; acc[3][2]+=a4.w*b4.z; acc[3][3]+=a4.w*b4.w;
    }
    __syncthreads();
  }
  float4 bb = *(const float4*)(bias + bx*64 + tx*4);
#pragma unroll
  for (int i = 0; i < 4; ++i) {
    float4 o;
    o.x = acc[i][0]+bb.x; o.y = acc[i][1]+bb.y; o.z = acc[i][2]+bb.z; o.w = acc[i][3]+bb.w;
    *(float4*)(C + (size_t)(by*64+ty*4+i)*Nc + bx*64 + tx*4) = o;
  }
}

// ---------------- GEMM #2 (output): A rows live in Uh[t][e] layout.
__global__ __launch_bounds__(256) void gemm_out(
    const float* __restrict__ A, const float* __restrict__ B,
    const float* __restrict__ bias, float* __restrict__ C)
{
  __shared__ float As[16][68];
  __shared__ float Bs[16][68];
  const int tid = threadIdx.x;
  const int bx = blockIdx.x, by = blockIdx.y;
  const int tx = tid & 15, ty = tid >> 4;
  const int am = tid >> 2, ak = (tid & 3) * 4;
  const int bk = tid >> 4, bn = (tid & 15) * 4;
  float acc[4][4] = {};
  const int arow = by*64 + am;
  const float* Ap = A + (size_t)(arow >> 5)*UHT + (size_t)(arow & 31)*768 + ak;
  const float* Bp = B + (size_t)bk*512 + bx*64 + bn;
  for (int k0 = 0; k0 < 768; k0 += 16) {
    float4 av = *(const float4*)Ap; Ap += 16;
    float4 bv = *(const float4*)Bp; Bp += (size_t)16*512;
    As[ak+0][am]=av.x; As[ak+1][am]=av.y; As[ak+2][am]=av.z; As[ak+3][am]=av.w;
    *(float4*)&Bs[bk][bn] = bv;
    __syncthreads();
#pragma unroll
    for (int kk = 0; kk < 16; ++kk) {
      float4 a4 = *(const float4*)&As[kk][ty*4];
      float4 b4 = *(const float4*)&Bs[kk][tx*4];
      acc[0][0]+=a4.x*b4.x; acc[0][1]+=a4.x*b4.y; acc[0][2]+=a4.x*b4.z; acc[0][3]+=a4.x*b4.w;
      acc[1][0]+=a4.y*b4.x; acc[1][1]+=a4.y*b4.y; acc[1][2]+=a4.y*b4.z; acc[1][3]+=a4.y*b4.w;
      acc[2][0]+=a4.z*b4.x; acc[2][1]+=a4.z*b4.y; acc[2][2]+=a4.z*b4.z; acc[2][3]+=a4.z*b4.w;
      acc[3][0]+=a4.w*b4.x; acc[3][1]+=a4.w*b4.y; acc[3][2]+=a4.w*b4.z; acc[3][3]+=a4.w*b4.w;
    }
    __syncthreads();
  }
  float4 bb = *(const float4*)(bias + bx*64 + tx*4);
#pragma unroll
  for (int i = 0; i < 4; ++i) {
    int row = by*64 + ty*4 + i;
    int crow = (row & 31)*128 + (row >> 5);   // (e,t) -> e*128+t
    float4 o;
    o.x = acc[i][0]+bb.x; o.y = acc[i][1]+bb.y; o.z = acc[i][2]+bb.z; o.w = acc[i][3]+bb.w;
    *(float4*)(C + (size_t)crow*512 + bx*64 + tx*4) = o;
  }
}

// ---------------- state-block LDS layout (floats)
#define SL_L    0          // 128*130 = 16640
#define SL_M    16640      // 128*66  = 8448
#define SL_V    25088      // 480
#define SL_WR   25568      // 512
#define SL_FW   26080      // 512
#define SL_BW   26592      // 512
#define SL_CR   27104      // 512
#define SL_USG  27616      // 128
#define SL_PRC  27744      // 128
#define SL_WW   27872      // 128
#define SL_SU   28000      // 128
#define SL_CPX  28128      // 128
#define SL_MN   28256      // 128
#define SL_SW   28384      // 128
#define SL_CW   28512      // 128
#define SL_RNK  28640      // 128
#define SL_MSC  28768      // 64
#define SL_ER   28832      // 64
#define SL_WV   28896      // 64
#define SL_TOT  28960

// ---------------- col-block LDS layout
// Wzu: uint[76][390]  (bf16-pair z-weights; even stride, aligned uint2 reads)
// Wiu: uint[17][262]
// us:  float[4][772]  (reads 0..255, h 256..767)  [base 34096 ≡ 0 mod 4: 16B aligned]
// zh:  float[4][76] ; cst: float[76]
#define CWI_U  29640
#define CUS_F  34096
#define CZH_F  37184
#define CCS_F  37488
#define CTOT_F 37564   // 150256 B

__global__ void init_flags(unsigned* flags) {
  int idx = blockIdx.x*1024 + threadIdx.x;
  if (idx < NFLAGS)
    __hip_atomic_store(&flags[idx], 0u, __ATOMIC_RELAXED, __HIP_MEMORY_SCOPE_AGENT);
}

__global__ __launch_bounds__(1024) void dnc_coop(
    const float* __restrict__ Xproj, const float* __restrict__ Wx,
    const float* __restrict__ Wh, const float* __restrict__ Wif,
    const float* __restrict__ bif,
    float* __restrict__ Uh, float* __restrict__ Vh,
    unsigned* __restrict__ flags)
{
  const int blk = blockIdx.x, tid = threadIdx.x;
  extern __shared__ float sm[];
  const int g = blk & 7;          // group (heuristically = XCD via round-robin)
  const int role = blk >> 3;      // 0..31 within group
  unsigned* FHg = flags + (size_t)g*64*FSP;        // slots 0..27
  unsigned* FVg = FHg + 28*FSP;                    // slots 28..55
  unsigned* FRg = FHg + 56*FSP;                    // slots 56..59

  if (role < 4) {
    // ================= STATE BLOCK (example eg) =================
    const int eg = g*4 + role;
    float* L   = sm + SL_L;   float* Ms  = sm + SL_M;
    float* v   = sm + SL_V;   float* wr  = sm + SL_WR;
    float* fw  = sm + SL_FW;  float* bw  = sm + SL_BW;
    float* cr  = sm + SL_CR;  float* usg = sm + SL_USG;
    float* prc = sm + SL_PRC; float* ww  = sm + SL_WW;
    float* su  = sm + SL_SU;  float* cpx = sm + SL_CPX;
    float* Mn  = sm + SL_MN;  float* swv = sm + SL_SW;
    float* cw  = sm + SL_CW;  int*   rnk = (int*)(sm + SL_RNK);
    float* msc = sm + SL_MSC; float* er_ = sm + SL_ER; float* wv_ = sm + SL_WV;

    for (int i = tid; i < SL_TOT; i += 1024) sm[i] = 0.f;
    __syncthreads();

    for (int t = 0; t < TT; ++t) {
      wait_ge(FVg, 28, t+1);   // v(t) from this group's 28 col-blocks
      if (tid < IFC) v[tid] = Vh[(size_t)t*VHT + eg*480 + tid];
      __syncthreads();
      // B
      if (tid < 128) {
        float ret = 1.f;
#pragma unroll
        for (int r = 0; r < 4; ++r) { float fr = sig_(v[453+r]); ret *= 1.f - fr*wr[r*128+tid]; }
        float u = usg[tid], w_ = ww[tid];
        usg[tid] = (u + w_ - u*w_) * ret;
      } else if (tid < 256) {
        int n = tid - 128; float nk = 0.f, dot = 0.f;
#pragma unroll
        for (int w = 0; w < 64; w += 2) {
          float2 k2 = *(float2*)&v[260+w];
          float2 m2 = *(float2*)&Ms[n*MST+w];
          nk += k2.x*k2.x + k2.y*k2.y; dot += m2.x*k2.x + m2.y*k2.y;
        }
        float beta = 1.f + sp_(v[324]);
        swv[n] = beta * dot / ((Mn[n]+EPSF)*(sqrtf(nk)+EPSF));
      } else if (tid < 260) {
        int r = tid - 256; float s = 0.f;
#pragma unroll
        for (int w = 0; w < 64; w += 4) { float4 k4 = *(float4*)&v[r*64+w]; s += D4(k4,k4); }
        msc[1+r] = sqrtf(s);
      } else if (tid == 260) {
        for (int r = 0; r < 4; ++r) {
          float a0 = v[459+r*3], a1 = v[459+r*3+1], a2 = v[459+r*3+2];
          float mx = fmaxf(a0, fmaxf(a1, a2));
          float e0 = expf(a0-mx), e1 = expf(a1-mx), e2 = expf(a2-mx);
          float dn = e0+e1+e2;
          msc[8+r*3] = e0/dn; msc[8+r*3+1] = e1/dn; msc[8+r*3+2] = e2/dn;
        }
      } else if (tid >= 640 && tid < 704) { int w = tid-640; er_[w] = sig_(v[325+w]); }
      else if (tid >= 704 && tid < 768) { int w = tid-704; wv_[w] = v[389+w]; }
      __syncthreads();
      // C — rank (vectorized broadcast reads)
      if (tid < 128) {
        float ui = usg[tid]; int rk = 0;
#pragma unroll
        for (int j = 0; j < 128; j += 4) {
          float4 u4 = *(float4*)&usg[j];
          rk += (u4.x < ui || (u4.x == ui && (j+0) < tid)) ? 1 : 0;
          rk += (u4.y < ui || (u4.y == ui && (j+1) < tid)) ? 1 : 0;
          rk += (u4.z < ui || (u4.z == ui && (j+2) < tid)) ? 1 : 0;
          rk += (u4.w < ui || (u4.w == ui && (j+3) < tid)) ? 1 : 0;
        }
        rnk[tid] = rk; su[rk] = ui;
      } else if (tid < 192) {
        int l = tid - 128;
        float s1 = swv[l], s2 = swv[l+64];
        float m = fmaxf(s1, s2);
#pragma unroll
        for (int o = 32; o > 0; o >>= 1) m = fmaxf(m, __shfl_xor(m, o));
        float e1 = expf(s1-m), e2 = expf(s2-m);
        float dn = e1 + e2;
#pragma unroll
        for (int o = 32; o > 0; o >>= 1) dn += __shfl_xor(dn, o);
        cw[l] = e1/dn; cw[l+64] = e2/dn;
      }
      __syncthreads();
      // D' cumprod + ww (+fused ww-sum -> msc[0])
      if (tid < 64) {
        float a0 = su[2*tid], a1 = su[2*tid+1];
        float p = a0*a1, sc = p;
#pragma unroll
        for (int off = 1; off < 64; off <<= 1) {
          float o = __shfl_up(sc, off);
          if ((int)tid >= off) sc *= o;
        }
        float ex = __shfl_up(sc, 1);
        if (tid == 0) ex = 1.f;
        cpx[2*tid] = ex;
        cpx[2*tid+1] = ex*a0;
        float ag = sig_(v[457]), wg = sig_(v[458]);
        float wwa[2];
#pragma unroll
        for (int q = 0; q < 2; ++q) {
          int n = 2*tid + q;
          float a_i = (1.f - usg[n]) * cpx[rnk[n]];
          wwa[q] = wg * (ag*a_i + (1.f-ag)*cw[n]);
          ww[n] = wwa[q];
        }
        float s = wwa[0] + wwa[1];
#pragma unroll
        for (int o = 32; o > 0; o >>= 1) s += __shfl_xor(s, o);
        if (tid == 0) msc[0] = s;
      }
      __syncthreads();
      // F (+fused Mn of post-write M from register values)
      {
        int n = tid >> 3, q = tid & 7;
        float wwn = ww[n];
        int w8 = q*8;
        float sq = 0.f;
#pragma unroll
        for (int gq = 0; gq < 4; ++gq) {
          int w = w8 + gq*2;
          float2 m = *(float2*)&Ms[n*MST+w];
          float2 e2 = *(float2*)&er_[w];
          float2 v2 = *(float2*)&wv_[w];
          m.x = m.x*(1.f - wwn*e2.x) + wwn*v2.x;
          m.y = m.y*(1.f - wwn*e2.y) + wwn*v2.y;
          *(float2*)&Ms[n*MST+w] = m;
          sq += m.x*m.x + m.y*m.y;
        }
        sq += __shfl_xor(sq,1); sq += __shfl_xor(sq,2); sq += __shfl_xor(sq,4);
        if (q == 0) Mn[n] = sqrtf(sq);
        int j16 = q*16;
#pragma unroll
        for (int gq = 0; gq < 8; ++gq) {
          int j = j16 + gq*2;
          float2 lv = *(float2*)&L[n*LST + j];
          float2 p2 = *(float2*)&prc[j];
          float2 w2 = *(float2*)&ww[j];
          lv.x = (1.f - wwn - w2.x)*lv.x + wwn*p2.x;
          lv.y = (1.f - wwn - w2.y)*lv.y + wwn*p2.y;
          int d = n - j;
          if (d == 0) lv.x = 0.f;
          if (d == 1) lv.y = 0.f;
          *(float2*)&L[n*LST + j] = lv;
        }
      }
      __syncthreads();
      // H'
      if (tid < 256) {
        int half = tid >> 7, t2 = tid & 127;
        int i0 = (t2 >> 2) * 4, sg = t2 & 3;
        float4 av[4] = {{0,0,0,0},{0,0,0,0},{0,0,0,0},{0,0,0,0}};
        if (half == 0) {
#pragma unroll
          for (int m = 0; m < 8; ++m) {
            int j = sg*4 + m*16;
            float4 w0 = *(float4*)&wr[0*128+j];
            float4 w1 = *(float4*)&wr[1*128+j];
            float4 w2 = *(float4*)&wr[2*128+j];
            float4 w3 = *(float4*)&wr[3*128+j];
#pragma unroll
            for (int k = 0; k < 4; ++k) {
              float2 la = *(float2*)&L[(i0+k)*LST+j];
              float2 lb = *(float2*)&L[(i0+k)*LST+j+2];
              float dv0 = la.x*w0.x + la.y*w0.y + lb.x*w0.z + lb.y*w0.w;
              float dv1 = la.x*w1.x + la.y*w1.y + lb.x*w1.z + lb.y*w1.w;
              float dv2 = la.x*w2.x + la.y*w2.y + lb.x*w2.z + lb.y*w2.w;
              float dv3 = la.x*w3.x + la.y*w3.y + lb.x*w3.z + lb.y*w3.w;
              if (k == 0){ av[0].x+=dv0; av[1].x+=dv1; av[2].x+=dv2; av[3].x+=dv3; }
              if (k == 1){ av[0].y+=dv0; av[1].y+=dv1; av[2].y+=dv2; av[3].y+=dv3; }
              if (k == 2){ av[0].z+=dv0; av[1].z+=dv1; av[2].z+=dv2; av[3].z+=dv3; }
              if (k == 3){ av[0].w+=dv0; av[1].w+=dv1; av[2].w+=dv2; av[3].w+=dv3; }
            }
          }
        } else {
#pragma unroll
          for (int m = 0; m < 32; ++m) {
            int j = sg + m*4;
            float2 la = *(float2*)&L[j*LST + i0];
            float2 lb = *(float2*)&L[j*LST + i0 + 2];
            float w0 = wr[j], w1 = wr[128+j], w2 = wr[256+j], w3 = wr[384+j];
            av[0].x+=w0*la.x; av[0].y+=w0*la.y; av[0].z+=w0*lb.x; av[0].w+=w0*lb.y;
            av[1].x+=w1*la.x; av[1].y+=w1*la.y; av[1].z+=w1*lb.x; av[1].w+=w1*lb.y;
            av[2].x+=w2*la.x; av[2].y+=w2*la.y; av[2].z+=w2*lb.x; av[2].w+=w2*lb.y;
            av[3].x+=w3*la.x; av[3].y+=w3*la.y; av[3].z+=w3*lb.x; av[3].w+=w3*lb.y;
          }
        }
#pragma unroll
        for (int r = 0; r < 4; ++r) {
          av[r].x += __shfl_xor(av[r].x,1); av[r].x += __shfl_xor(av[r].x,2);
          av[r].y += __shfl_xor(av[r].y,1); av[r].y += __shfl_xor(av[r].y,2);
          av[r].z += __shfl_xor(av[r].z,1); av[r].z += __shfl_xor(av[r].z,2);
          av[r].w += __shfl_xor(av[r].w,1); av[r].w += __shfl_xor(av[r].w,2);
        }
        if (sg == 0) {
          float* dst = half ? bw : fw;
#pragma unroll
          for (int r = 0; r < 4; ++r) {
            dst[r*128 + i0+0] = av[r].x; dst[r*128 + i0+1] = av[r].y;
            dst[r*128 + i0+2] = av[r].z; dst[r*128 + i0+3] = av[r].w;
          }
        }
      } else if (tid < 384) {
        int n = tid - 256;
        prc[n] = (1.f - msc[0])*prc[n] + ww[n];
      } else if (tid >= 512) {
        int r = (tid >> 7) & 3, n = tid & 127;
        float dot = 0.f;
#pragma unroll
        for (int w = 0; w < 64; w += 2) {
          float2 m2 = *(float2*)&Ms[n*MST+w];
          float2 k2 = *(float2*)&v[r*64+w];
          dot += m2.x*k2.x + m2.y*k2.y;
        }
        float beta = 1.f + sp_(v[256+r]);
        cr[r*128+n] = beta * dot / ((Mn[n]+EPSF)*(msc[1+r]+EPSF));
      }
      __syncthreads();
      // J'
      if (tid < 256) {
        int r = tid >> 6, l = tid & 63;
        float s1 = cr[r*128+l], s2 = cr[r*128+l+64];
        float m = fmaxf(s1, s2);
#pragma unroll
        for (int o = 32; o > 0; o >>= 1) m = fmaxf(m, __shfl_xor(m, o));
        float e1 = expf(s1-m), e2 = expf(s2-m);
        float dn = e1 + e2;
#pragma unroll
        for (int o = 32; o > 0; o >>= 1) dn += __shfl_xor(dn, o);
        float m0 = msc[8+r*3], m1 = msc[8+r*3+1], m2 = msc[8+r*3+2];
        wr[r*128+l]    = m0*bw[r*128+l]    + m1*(e1/dn) + m2*fw[r*128+l];
        wr[r*128+l+64] = m0*bw[r*128+l+64] + m1*(e2/dn) + m2*fw[r*128+l+64];
      }
      __syncthreads();
      // L: reads publish
      if (tid < 512) {
        int r = tid >> 7, t2 = tid & 127;
        int w0 = (t2 >> 3) * 4, ns = t2 & 7;
        float4 a = {0,0,0,0};
#pragma unroll
        for (int m = 0; m < 16; ++m) {
          int n = ns + m*8;
          float2 ma = *(float2*)&Ms[n*MST + w0];
          float2 mb = *(float2*)&Ms[n*MST + w0 + 2];
          float wv = wr[r*128 + n];
          a.x += wv*ma.x; a.y += wv*ma.y; a.z += wv*mb.x; a.w += wv*mb.y;
        }
        a.x += __shfl_xor(a.x,1); a.x += __shfl_xor(a.x,2); a.x += __shfl_xor(a.x,4);
        a.y += __shfl_xor(a.y,1); a.y += __shfl_xor(a.y,2); a.y += __shfl_xor(a.y,4);
        a.z += __shfl_xor(a.z,1); a.z += __shfl_xor(a.z,2); a.z += __shfl_xor(a.z,4);
        a.w += __shfl_xor(a.w,1); a.w += __shfl_xor(a.w,2); a.w += __shfl_xor(a.w,4);
        if (ns == 0) {
          int o = r*64 + w0;
          float2 lo = {a.x, a.y}, hi = {a.z, a.w};
          st2(&Uh[(size_t)t*UHT + eg*768 + o], lo);
          st2(&Uh[(size_t)t*UHT + eg*768 + o + 2], hi);
        }
      }
      arrive(&FRg[role*FSP], t+1);   // reads(t) published
    }
  } else {
    // ======== COL BLOCK c: h-dims [d0,d1) x 4 gate quadrants + v-cols [v0,v1) ====
    const int c = role - 4;                       // 0..27
    const int egB = g*4;                          // group's first example
    const int d0 = (512*c)/28, d1 = (512*(c+1))/28, Dd = d1-d0, NJ = 4*Dd;
    const int v0 = (471*c)/28, v1 = (471*(c+1))/28, JV = v1-v0;
    unsigned* Wzu = (unsigned*)sm;                // [76][390]
    unsigned* Wiu = (unsigned*)sm + CWI_U;        // [17][262]
    float* us  = sm + CUS_F;                      // [4][772]  16B-aligned base
    float* zh  = sm + CZH_F;                      // [4][76]
    float* cst = sm + CCS_F;                      // [76]

    // ---- one-time: pack weights to bf16 pairs in LDS
    for (int idx = tid; idx < NJ*384; idx += 1024) {
      int j = idx/384, p = idx - j*384, k = 2*p;
      int q = j/Dd, di = j - q*Dd, gc = q*512 + d0 + di;
      float w0 = (k < 256) ? Wx[(size_t)(512+k)*ZD + gc] : Wh[(size_t)(k-256)*ZD + gc];
      float w1 = (k+1 < 256) ? Wx[(size_t)(513+k)*ZD + gc] : Wh[(size_t)(k-255)*ZD + gc];
      Wzu[j*390 + p] = bf16rne(w0) | (bf16rne(w1) << 16);
    }
    for (int idx = tid; idx < JV*256; idx += 1024) {
      int j = idx/256, p = idx - j*256, k = 2*p, gc = v0 + j;
      float w0 = Wif[(size_t)k*IFC + gc];
      float w1 = Wif[(size_t)(k+1)*IFC + gc];
      Wiu[j*262 + p] = bf16rne(w0) | (bf16rne(w1) << 16);
    }
    if (tid < 76) cst[tid] = 0.f;
    // bootstrap z(0) = Xproj(0)
    if (tid < 4*NJ) {
      int e = tid/NJ, j = tid - e*NJ;
      int q = j/Dd, di = j - q*Dd, gc = q*512 + d0 + di;
      zh[e*76 + j] = Xproj[((size_t)(egB+e)*TT + 0)*ZD + gc];
    }
    __syncthreads();
    if (tid < 4*Dd) {
      int e = tid/Dd, di = tid - e*Dd;
      float zi = zh[e*76 + di], zg = zh[e*76 + 2*Dd + di], zo = zh[e*76 + 3*Dd + di];
      float cn = sig_(zi)*tanhf(zg);
      float hn = sig_(zo)*tanhf(cn);
      cst[tid] = cn;
      st1(&Uh[(size_t)0*UHT + (egB + e)*768 + 256 + d0 + di], hn);
    }
    arrive(&FHg[c*FSP], 1);   // h(0) published

    for (int t = 0; t < TT; ++t) {
      // prefetch Xproj(t+1) into registers BEFORE the wait (hides HBM latency)
      float xpre = 0.f; int pe = 0, pj = 0;
      if (t+1 < TT && tid < 4*NJ) {
        pe = tid/NJ; pj = tid - pe*NJ;
        int q = pj/Dd, di = pj - q*Dd, gc = q*512 + d0 + di;
        xpre = Xproj[((size_t)(egB+pe)*TT + t+1)*ZD + gc];
      }
      wait_ge(FHg, 28, t+1);   // h(t) complete (group-local)
      // stage h(t): fresh per-t region, plain cached float4 (16B-aligned dest)
      if (tid < 512) {
        int e = tid >> 7, f4 = (tid & 127) * 4;
        *(float4*)&us[e*772 + 256 + f4] =
            *(const float4*)&Uh[(size_t)t*UHT + (egB+e)*768 + 256 + f4];
      }
      // zh(t+1) init from prefetched Xproj
      if (t+1 < TT && tid < 4*NJ) {
        zh[pe*76 + pj] = xpre;
      }
      __syncthreads();
      // v-gemm: 4e x JV cols, K=512, 8-way k-split, b64 weights + b128 activations
      if (tid < 544) {
        int g8 = tid >> 3, ks = tid & 7;
        int e = g8/17, j = g8 - e*17;
        if (j < JV) {
          float acc = 0.f;
#pragma unroll 4
          for (int m = 0; m < 16; ++m) {
            int p = m*16 + ks*2;
            float4 hv = *(const float4*)&us[e*772 + 256 + 2*p];
            uint2 wu = *(const uint2*)&Wiu[j*262 + p];
            acc += hv.x*bflo(wu.x) + hv.y*bfhi(wu.x)
                 + hv.z*bflo(wu.y) + hv.w*bfhi(wu.y);
          }
          acc += __shfl_xor(acc,1); acc += __shfl_xor(acc,2); acc += __shfl_xor(acc,4);
          if (ks == 0) {
            int col = v0 + j;
            st1(&Vh[(size_t)t*VHT + (egB+e)*480 + col], bif[col] + acc);
          }
        }
      }
      arrive(&FVg[c*FSP], t+1);   // v(t) published
      if (t+1 < TT) {
        // hop 2 overlapped CROSS-WAVE: z-Wh gemm on waves 0-9 (tid<608) runs
        // CONCURRENTLY with FR-gated reads staging on waves 10-13 (tid 640-895,
        // one FR flag per wave); one barrier joins them.
        if (tid < 608) {
          int q2 = tid >> 1, ks = tid & 1;
          int e = q2/76, j = q2 - e*76;
          if (j < NJ) {
            float acc = 0.f;
#pragma unroll 4
            for (int m = 0; m < 64; ++m) {
              int p = 128 + m*4 + ks*2;
              float4 hv = *(const float4*)&us[e*772 + 2*p];   // 2p>=256 -> h region
              uint2 wu = *(const uint2*)&Wzu[j*390 + p];
              acc += hv.x*bflo(wu.x) + hv.y*bfhi(wu.x)
                   + hv.z*bflo(wu.y) + hv.w*bfhi(wu.y);
            }
            acc += __shfl_xor(acc,1);
            if (ks == 0) zh[e*76 + j] += acc;
          }
        } else if (tid >= 640 && tid < 896) {
          int e2 = (tid - 640) >> 6, f4b = ((tid - 640) & 63) * 4;
          spin1(&FRg[e2*FSP], t+1);   // whole wave spins on ONE flag
          *(float4*)&us[e2*772 + f4b] =
              *(const float4*)&Uh[(size_t)t*UHT + (egB+e2)*768 + f4b];
        }
        __syncthreads();
        // z += reads(t) @ WxR-part (K=256) — b64 weights + b128 activations
        if (tid < 608) {
          int q2 = tid >> 1, ks = tid & 1;
          int e = q2/76, j = q2 - e*76;
          if (j < NJ) {
            float acc = 0.f;
#pragma unroll 4
            for (int m = 0; m < 32; ++m) {
              int p = m*4 + ks*2;
              float4 rv = *(const float4*)&us[e*772 + 2*p];
              uint2 wu = *(const uint2*)&Wzu[j*390 + p];
              acc += rv.x*bflo(wu.x) + rv.y*bfhi(wu.x)
                   + rv.z*bflo(wu.y) + rv.w*bfhi(wu.y);
            }
            acc += __shfl_xor(acc,1);
            if (ks == 0) zh[e*76 + j] += acc;
          }
        }
        __syncthreads();
        // gates -> h(t+1), publish
        if (tid < 4*Dd) {
          int e = tid/Dd, di = tid - e*Dd;
          float zi = zh[e*76 + di],      zf = zh[e*76 + Dd + di];
          float zg = zh[e*76 + 2*Dd+di], zo = zh[e*76 + 3*Dd + di];
          float cn = sig_(zf)*cst[tid] + sig_(zi)*tanhf(zg);
          float hn = sig_(zo)*tanhf(cn);
          cst[tid] = cn;
          st1(&Uh[(size_t)(t+1)*UHT + (egB+e)*768 + 256 + d0 + di], hn);
        }
        arrive(&FHg[c*FSP], t+2);   // h(t+1) published
      }
    }
  }
}

extern "C" void kernel_launch(void* const* d_in, const int* in_sizes, int n_in,
                              void* d_out, int out_size, void* d_ws, size_t ws_size,
                              hipStream_t stream) {
  const float* x   = (const float*)d_in[0];
  const float* Wx  = (const float*)d_in[1];
  const float* Wh  = (const float*)d_in[2];
  const float* bl  = (const float*)d_in[3];
  const float* Wif = (const float*)d_in[4];
  const float* bif = (const float*)d_in[5];
  const float* Wo  = (const float*)d_in[6];
  const float* bo  = (const float*)d_in[7];
  float* out = (float*)d_out;

  unsigned* fl = (unsigned*)d_ws;                   // 8192 uints = 32KB (cacheline-spaced flags)
  float* Xp = (float*)(fl + NFLAGS);                // 4096*2048
  float* Uh = Xp + (size_t)4096*2048;               // 128*UHT
  float* Vh = Uh + (size_t)TT*UHT;                  // 128*VHT

  // 1) Xproj = x @ Wx[:512] + b_lstm
  gemm_bias<<<dim3(2048/64, 4096/64), dim3(256), 0, stream>>>(x, Wx, bl, Xp, 2048, 512);

  // 2) flags
  init_flags<<<dim3(8), dim3(1024), 0, stream>>>(fl);

  // 3) XCD-sharded cooperative core: 8 groups x (4 state + 28 col) blocks
  const int smem_bytes = CTOT_F * 4;  // 150256
  (void)hipFuncSetAttribute((const void*)dnc_coop, hipFuncAttributeMaxDynamicSharedMemorySize, smem_bytes);
  void* args[] = { (void*)&Xp, (void*)&Wx, (void*)&Wh, (void*)&Wif, (void*)&bif,
                   (void*)&Uh, (void*)&Vh, (void*)&fl };
  (void)hipLaunchCooperativeKernel((void*)dnc_coop, dim3(NBLK), dim3(1024), args,
                                   (unsigned int)smem_bytes, stream);

  // 4) out = [reads,h] @ W_out + b_out
  gemm_out<<<dim3(512/64, 4096/64), dim3(256), 0, stream>>>(Uh, Wo, bo, out);
}

// Round 11
// 3944.064 us; speedup vs baseline: 1.0374x; 1.0088x over previous
//
#include <hip/hip_runtime.h>
#include <math.h>

#define TT 128
#define ZD 2048
#define IFC 471
#define EPSF 1e-6f
#define MST 66      // M LDS row stride (66 ≡ 2 mod 32)
#define LST 130     // link LDS row stride (130 ≡ 2 mod 32)
#define NBLK 256
#define UHT 24640   // per-t stride of Uh: 32*768 + 64 guard floats
#define VHT 15424   // per-t stride of Vh: 32*480 + 64 guard floats

// flags: one per 64B cacheline (FSP=16 uints). Per group 64 slots:
// [0..27]=FH (col h arrivals) [28..55]=FV (col v arrivals) [56..59]=FR (state reads)
#define FSP 16
#define NFLAGS 8192   // 8 groups * 64 slots * 16 uints = 32KB

#define D4(a,b) ((a).x*(b).x + (a).y*(b).y + (a).z*(b).z + (a).w*(b).w)

__device__ __forceinline__ float sig_(float x){ return 1.f/(1.f+expf(-x)); }
__device__ __forceinline__ float sp_(float x){ return fmaxf(x,0.f)+log1pf(expf(-fabsf(x))); }

// -------- agent-scope (write-through) publishes: correct on ANY placement --
__device__ __forceinline__ void st1(float* p, float v){
  unsigned u; __builtin_memcpy(&u,&v,4);
  __hip_atomic_store((unsigned*)p, u, __ATOMIC_RELAXED, __HIP_MEMORY_SCOPE_AGENT);
}
__device__ __forceinline__ void st2(float* p, float2 v){
  unsigned long long u; __builtin_memcpy(&u,&v,8);
  __hip_atomic_store((unsigned long long*)p, u, __ATOMIC_RELAXED, __HIP_MEMORY_SCOPE_AGENT);
}

// -------- dataflow sync: single-writer flags, plain agent store of generation.
__device__ __forceinline__ void arrive(unsigned* f, unsigned gen){
  __syncthreads();   // drains vmcnt(0): payload stores coherent before flag store
  if (threadIdx.x == 0)
    __hip_atomic_store(f, gen, __ATOMIC_RELAXED, __HIP_MEMORY_SCOPE_AGENT);
}
__device__ __forceinline__ void wait_ge(const unsigned* f, int n, unsigned gen){
  if (threadIdx.x < 64){
    for (int i = threadIdx.x; i < n; i += 64){
      const unsigned* p = f + (size_t)i*FSP;
      if (__hip_atomic_load(p, __ATOMIC_RELAXED, __HIP_MEMORY_SCOPE_AGENT) >= gen) continue;
      int spins = 0; bool done = false;
      while (spins < 64){
        if (__hip_atomic_load(p, __ATOMIC_RELAXED, __HIP_MEMORY_SCOPE_AGENT) >= gen){ done = true; break; }
        __builtin_amdgcn_s_sleep(1); ++spins;
      }
      if (!done){
        while (__hip_atomic_load(p, __ATOMIC_RELAXED, __HIP_MEMORY_SCOPE_AGENT) < gen)
          __builtin_amdgcn_s_sleep(2);
      }
    }
  }
  __syncthreads();
}

__device__ __forceinline__ unsigned bf16rne(float f){
  unsigned u; __builtin_memcpy(&u,&f,4);
  return (u + 0x7fffu + ((u>>16)&1u)) >> 16;
}
__device__ __forceinline__ float bflo(unsigned w){
  unsigned u = w << 16; float f; __builtin_memcpy(&f,&u,4); return f;
}
__device__ __forceinline__ float bfhi(unsigned w){
  unsigned u = w & 0xffff0000u; float f; __builtin_memcpy(&f,&u,4); return f;
}

// ---------------- GEMM #1: C[M,N] = A[M,K] @ B[K,N] + bias[N]
__global__ __launch_bounds__(256) void gemm_bias(
    const float* __restrict__ A, const float* __restrict__ B,
    const float* __restrict__ bias, float* __restrict__ C,
    int Nc, int K)
{
  __shared__ float As[16][68];
  __shared__ float Bs[16][68];
  const int tid = threadIdx.x;
  const int bx = blockIdx.x, by = blockIdx.y;
  const int tx = tid & 15, ty = tid >> 4;
  const int am = tid >> 2, ak = (tid & 3) * 4;
  const int bk = tid >> 4, bn = (tid & 15) * 4;
  float acc[4][4] = {};
  const float* Ap = A + (size_t)(by*64+am)*K + ak;
  const float* Bp = B + (size_t)bk*Nc + bx*64 + bn;
  for (int k0 = 0; k0 < K; k0 += 16) {
    float4 av = *(const float4*)Ap; Ap += 16;
    float4 bv = *(const float4*)Bp; Bp += (size_t)16*Nc;
    As[ak+0][am]=av.x; As[ak+1][am]=av.y; As[ak+2][am]=av.z; As[ak+3][am]=av.w;
    *(float4*)&Bs[bk][bn] = bv;
    __syncthreads();
#pragma unroll
    for (int kk = 0; kk < 16; ++kk) {
      float4 a4 = *(const float4*)&As[kk][ty*4];
      float4 b4 = *(const float4*)&Bs[kk][tx*4];
      acc[0][0]+=a4.x*b4.x; acc[0][1]+=a4.x*b4.y; acc[0][2]+=a4.x*b4.z; acc[0][3]+=a4.x*b4.w;
      acc[1][0]+=a4.y*b4.x; acc[1][1]+=a4.y*b4.y; acc[1][2]+=a4.y*b4.z; acc[1][3]+=a4.y*b4.w;
      acc[2][0]+=a4.z*b4.x; acc[2][1]+=a4.z*b4.y; acc[2][2]+=a4.z*b4.z; acc[2][3]+=a4.z*b4.w;
      acc[3][0]+=a4.w*b4.x; acc[3][1]+=a4.w*b4.y; acc[3][2]+=a4.w*b4.z; acc[3][3]+=a4.w*b4.w;
    }
    __syncthreads();
  }
  float4 bb = *(const float4*)(bias + bx*64 + tx*4);
#pragma unroll
  for (int i = 0; i < 4; ++i) {
    float4 o;
    o.x = acc[i][0]+bb.x; o.y = acc[i][1]+bb.y; o.z = acc[i][2]+bb.z; o.w = acc[i][3]+bb.w;
    *(float4*)(C + (size_t)(by*64+ty*4+i)*Nc + bx*64 + tx*4) = o;
  }
}

// ---------------- GEMM #2 (output): A rows live in Uh[t][e] layout.
__global__ __launch_bounds__(256) void gemm_out(
    const float* __restrict__ A, const float* __restrict__ B,
    const float* __restrict__ bias, float* __restrict__ C)
{
  __shared__ float As[16][68];
  __shared__ float Bs[16][68];
  const int tid = threadIdx.x;
  const int bx = blockIdx.x, by = blockIdx.y;
  const int tx = tid & 15, ty = tid >> 4;
  const int am = tid >> 2, ak = (tid & 3) * 4;
  const int bk = tid >> 4, bn = (tid & 15) * 4;
  float acc[4][4] = {};
  const int arow = by*64 + am;
  const float* Ap = A + (size_t)(arow >> 5)*UHT + (size_t)(arow & 31)*768 + ak;
  const float* Bp = B + (size_t)bk*512 + bx*64 + bn;
  for (int k0 = 0; k0 < 768; k0 += 16) {
    float4 av = *(const float4*)Ap; Ap += 16;
    float4 bv = *(const float4*)Bp; Bp += (size_t)16*512;
    As[ak+0][am]=av.x; As[ak+1][am]=av.y; As[ak+2][am]=av.z; As[ak+3][am]=av.w;
    *(float4*)&Bs[bk][bn] = bv;
    __syncthreads();
#pragma unroll
    for (int kk = 0; kk < 16; ++kk) {
      float4 a4 = *(const float4*)&As[kk][ty*4];
      float4 b4 = *(const float4*)&Bs[kk][tx*4];
      acc[0][0]+=a4.x*b4.x; acc[0][1]+=a4.x*b4.y; acc[0][2]+=a4.x*b4.z; acc[0][3]+=a4.x*b4.w;
      acc[1][0]+=a4.y*b4.x; acc[1][1]+=a4.y*b4.y; acc[1][2]+=a4.y*b4.z; acc[1][3]+=a4.y*b4.w;
      acc[2][0]+=a4.z*b4.x; acc[2][1]+=a4.z*b4.y; acc[2][2]+=a4.z*b4.z; acc[2][3]+=a4.z*b4.w;
      acc[3][0]+=a4.w*b4.x; acc[3][1]+=a4.w*b4.y; acc[3][2]+=a4.w*b4.z; acc[3][3]+=a4.w*b4.w;
    }
    __syncthreads();
  }
  float4 bb = *(const float4*)(bias + bx*64 + tx*4);
#pragma unroll
  for (int i = 0; i < 4; ++i) {
    int row = by*64 + ty*4 + i;
    int crow = (row & 31)*128 + (row >> 5);   // (e,t) -> e*128+t
    float4 o;
    o.x = acc[i][0]+bb.x; o.y = acc[i][1]+bb.y; o.z = acc[i][2]+bb.z; o.w = acc[i][3]+bb.w;
    *(float4*)(C + (size_t)crow*512 + bx*64 + tx*4) = o;
  }
}

// ---------------- state-block LDS layout (floats)
#define SL_L    0          // 128*130 = 16640
#define SL_M    16640      // 128*66  = 8448
#define SL_V    25088      // 480
#define SL_WR   25568      // 512
#define SL_FW   26080      // 512
#define SL_BW   26592      // 512
#define SL_CR   27104      // 512
#define SL_USG  27616      // 128
#define SL_PRC  27744      // 128
#define SL_WW   27872      // 128
#define SL_SU   28000      // 128
#define SL_CPX  28128      // 128
#define SL_MN   28256      // 128
#define SL_SW   28384      // 128
#define SL_CW   28512      // 128
#define SL_RNK  28640      // 128
#define SL_MSC  28768      // 64
#define SL_ER   28832      // 64
#define SL_WV   28896      // 64
#define SL_TOT  28960

// ---------------- col-block LDS layout
// Wzu: uint[76][390]  (bf16-pair z-weights; even stride, aligned uint2 reads)
// Wiu: uint[17][262]
// us:  float[4][772]  (reads 0..255, h 256..767)  [base 34096 ≡ 0 mod 4: 16B aligned]
// zh:  float[4][76] ; cst: float[76]
#define CWI_U  29640
#define CUS_F  34096
#define CZH_F  37184
#define CCS_F  37488
#define CTOT_F 37564   // 150256 B

__global__ void init_flags(unsigned* flags) {
  int idx = blockIdx.x*1024 + threadIdx.x;
  if (idx < NFLAGS)
    __hip_atomic_store(&flags[idx], 0u, __ATOMIC_RELAXED, __HIP_MEMORY_SCOPE_AGENT);
}

__global__ __launch_bounds__(1024) void dnc_coop(
    const float* __restrict__ Xproj, const float* __restrict__ Wx,
    const float* __restrict__ Wh, const float* __restrict__ Wif,
    const float* __restrict__ bif,
    float* __restrict__ Uh, float* __restrict__ Vh,
    unsigned* __restrict__ flags)
{
  const int blk = blockIdx.x, tid = threadIdx.x;
  extern __shared__ float sm[];
  const int g = blk & 7;          // group (heuristically = XCD via round-robin)
  const int role = blk >> 3;      // 0..31 within group
  unsigned* FHg = flags + (size_t)g*64*FSP;        // slots 0..27
  unsigned* FVg = FHg + 28*FSP;                    // slots 28..55
  unsigned* FRg = FHg + 56*FSP;                    // slots 56..59

  if (role < 4) {
    // ================= STATE BLOCK (example eg) =================
    const int eg = g*4 + role;
    float* L   = sm + SL_L;   float* Ms  = sm + SL_M;
    float* v   = sm + SL_V;   float* wr  = sm + SL_WR;
    float* fw  = sm + SL_FW;  float* bw  = sm + SL_BW;
    float* cr  = sm + SL_CR;  float* usg = sm + SL_USG;
    float* prc = sm + SL_PRC; float* ww  = sm + SL_WW;
    float* su  = sm + SL_SU;  float* cpx = sm + SL_CPX;
    float* Mn  = sm + SL_MN;  float* swv = sm + SL_SW;
    float* cw  = sm + SL_CW;  int*   rnk = (int*)(sm + SL_RNK);
    float* msc = sm + SL_MSC; float* er_ = sm + SL_ER; float* wv_ = sm + SL_WV;

    for (int i = tid; i < SL_TOT; i += 1024) sm[i] = 0.f;
    __syncthreads();

    for (int t = 0; t < TT; ++t) {
      wait_ge(FVg, 28, t+1);   // v(t) from this group's 28 col-blocks
      if (tid < IFC) v[tid] = Vh[(size_t)t*VHT + eg*480 + tid];
      __syncthreads();
      // B
      if (tid < 128) {
        float ret = 1.f;
#pragma unroll
        for (int r = 0; r < 4; ++r) { float fr = sig_(v[453+r]); ret *= 1.f - fr*wr[r*128+tid]; }
        float u = usg[tid], w_ = ww[tid];
        usg[tid] = (u + w_ - u*w_) * ret;
      } else if (tid < 256) {
        int n = tid - 128; float nk = 0.f, dot = 0.f;
#pragma unroll
        for (int w = 0; w < 64; w += 2) {
          float2 k2 = *(float2*)&v[260+w];
          float2 m2 = *(float2*)&Ms[n*MST+w];
          nk += k2.x*k2.x + k2.y*k2.y; dot += m2.x*k2.x + m2.y*k2.y;
        }
        float beta = 1.f + sp_(v[324]);
        swv[n] = beta * dot / ((Mn[n]+EPSF)*(sqrtf(nk)+EPSF));
      } else if (tid < 260) {
        int r = tid - 256; float s = 0.f;
#pragma unroll
        for (int w = 0; w < 64; w += 4) { float4 k4 = *(float4*)&v[r*64+w]; s += D4(k4,k4); }
        msc[1+r] = sqrtf(s);
      } else if (tid == 260) {
        for (int r = 0; r < 4; ++r) {
          float a0 = v[459+r*3], a1 = v[459+r*3+1], a2 = v[459+r*3+2];
          float mx = fmaxf(a0, fmaxf(a1, a2));
          float e0 = expf(a0-mx), e1 = expf(a1-mx), e2 = expf(a2-mx);
          float dn = e0+e1+e2;
          msc[8+r*3] = e0/dn; msc[8+r*3+1] = e1/dn; msc[8+r*3+2] = e2/dn;
        }
      } else if (tid >= 640 && tid < 704) { int w = tid-640; er_[w] = sig_(v[325+w]); }
      else if (tid >= 704 && tid < 768) { int w = tid-704; wv_[w] = v[389+w]; }
      __syncthreads();
      // C — rank (vectorized broadcast reads)
      if (tid < 128) {
        float ui = usg[tid]; int rk = 0;
#pragma unroll
        for (int j = 0; j < 128; j += 4) {
          float4 u4 = *(float4*)&usg[j];
          rk += (u4.x < ui || (u4.x == ui && (j+0) < tid)) ? 1 : 0;
          rk += (u4.y < ui || (u4.y == ui && (j+1) < tid)) ? 1 : 0;
          rk += (u4.z < ui || (u4.z == ui && (j+2) < tid)) ? 1 : 0;
          rk += (u4.w < ui || (u4.w == ui && (j+3) < tid)) ? 1 : 0;
        }
        rnk[tid] = rk; su[rk] = ui;
      } else if (tid < 192) {
        int l = tid - 128;
        float s1 = swv[l], s2 = swv[l+64];
        float m = fmaxf(s1, s2);
#pragma unroll
        for (int o = 32; o > 0; o >>= 1) m = fmaxf(m, __shfl_xor(m, o));
        float e1 = expf(s1-m), e2 = expf(s2-m);
        float dn = e1 + e2;
#pragma unroll
        for (int o = 32; o > 0; o >>= 1) dn += __shfl_xor(dn, o);
        cw[l] = e1/dn; cw[l+64] = e2/dn;
      }
      __syncthreads();
      // D' cumprod + ww (+fused ww-sum -> msc[0])
      if (tid < 64) {
        float a0 = su[2*tid], a1 = su[2*tid+1];
        float p = a0*a1, sc = p;
#pragma unroll
        for (int off = 1; off < 64; off <<= 1) {
          float o = __shfl_up(sc, off);
          if ((int)tid >= off) sc *= o;
        }
        float ex = __shfl_up(sc, 1);
        if (tid == 0) ex = 1.f;
        cpx[2*tid] = ex;
        cpx[2*tid+1] = ex*a0;
        float ag = sig_(v[457]), wg = sig_(v[458]);
        float wwa[2];
#pragma unroll
        for (int q = 0; q < 2; ++q) {
          int n = 2*tid + q;
          float a_i = (1.f - usg[n]) * cpx[rnk[n]];
          wwa[q] = wg * (ag*a_i + (1.f-ag)*cw[n]);
          ww[n] = wwa[q];
        }
        float s = wwa[0] + wwa[1];
#pragma unroll
        for (int o = 32; o > 0; o >>= 1) s += __shfl_xor(s, o);
        if (tid == 0) msc[0] = s;
      }
      __syncthreads();
      // F (+fused Mn of post-write M from register values)
      {
        int n = tid >> 3, q = tid & 7;
        float wwn = ww[n];
        int w8 = q*8;
        float sq = 0.f;
#pragma unroll
        for (int gq = 0; gq < 4; ++gq) {
          int w = w8 + gq*2;
          float2 m = *(float2*)&Ms[n*MST+w];
          float2 e2 = *(float2*)&er_[w];
          float2 v2 = *(float2*)&wv_[w];
          m.x = m.x*(1.f - wwn*e2.x) + wwn*v2.x;
          m.y = m.y*(1.f - wwn*e2.y) + wwn*v2.y;
          *(float2*)&Ms[n*MST+w] = m;
          sq += m.x*m.x + m.y*m.y;
        }
        sq += __shfl_xor(sq,1); sq += __shfl_xor(sq,2); sq += __shfl_xor(sq,4);
        if (q == 0) Mn[n] = sqrtf(sq);
        int j16 = q*16;
#pragma unroll
        for (int gq = 0; gq < 8; ++gq) {
          int j = j16 + gq*2;
          float2 lv = *(float2*)&L[n*LST + j];
          float2 p2 = *(float2*)&prc[j];
          float2 w2 = *(float2*)&ww[j];
          lv.x = (1.f - wwn - w2.x)*lv.x + wwn*p2.x;
          lv.y = (1.f - wwn - w2.y)*lv.y + wwn*p2.y;
          int d = n - j;
          if (d == 0) lv.x = 0.f;
          if (d == 1) lv.y = 0.f;
          *(float2*)&L[n*LST + j] = lv;
        }
      }
      __syncthreads();
      // H'
      if (tid < 256) {
        int half = tid >> 7, t2 = tid & 127;
        int i0 = (t2 >> 2) * 4, sg = t2 & 3;
        float4 av[4] = {{0,0,0,0},{0,0,0,0},{0,0,0,0},{0,0,0,0}};
        if (half == 0) {
#pragma unroll
          for (int m = 0; m < 8; ++m) {
            int j = sg*4 + m*16;
            float4 w0 = *(float4*)&wr[0*128+j];
            float4 w1 = *(float4*)&wr[1*128+j];
            float4 w2 = *(float4*)&wr[2*128+j];
            float4 w3 = *(float4*)&wr[3*128+j];
#pragma unroll
            for (int k = 0; k < 4; ++k) {
              float2 la = *(float2*)&L[(i0+k)*LST+j];
              float2 lb = *(float2*)&L[(i0+k)*LST+j+2];
              float dv0 = la.x*w0.x + la.y*w0.y + lb.x*w0.z + lb.y*w0.w;
              float dv1 = la.x*w1.x + la.y*w1.y + lb.x*w1.z + lb.y*w1.w;
              float dv2 = la.x*w2.x + la.y*w2.y + lb.x*w2.z + lb.y*w2.w;
              float dv3 = la.x*w3.x + la.y*w3.y + lb.x*w3.z + lb.y*w3.w;
              if (k == 0){ av[0].x+=dv0; av[1].x+=dv1; av[2].x+=dv2; av[3].x+=dv3; }
              if (k == 1){ av[0].y+=dv0; av[1].y+=dv1; av[2].y+=dv2; av[3].y+=dv3; }
              if (k == 2){ av[0].z+=dv0; av[1].z+=dv1; av[2].z+=dv2; av[3].z+=dv3; }
              if (k == 3){ av[0].w+=dv0; av[1].w+=dv1; av[2].w+=dv2; av[3].w+=dv3; }
            }
          }
        } else {
#pragma unroll
          for (int m = 0; m < 32; ++m) {
            int j = sg + m*4;
            float2 la = *(float2*)&L[j*LST + i0];
            float2 lb = *(float2*)&L[j*LST + i0 + 2];
            float w0 = wr[j], w1 = wr[128+j], w2 = wr[256+j], w3 = wr[384+j];
            av[0].x+=w0*la.x; av[0].y+=w0*la.y; av[0].z+=w0*lb.x; av[0].w+=w0*lb.y;
            av[1].x+=w1*la.x; av[1].y+=w1*la.y; av[1].z+=w1*lb.x; av[1].w+=w1*lb.y;
            av[2].x+=w2*la.x; av[2].y+=w2*la.y; av[2].z+=w2*lb.x; av[2].w+=w2*lb.y;
            av[3].x+=w3*la.x; av[3].y+=w3*la.y; av[3].z+=w3*lb.x; av[3].w+=w3*lb.y;
          }
        }
#pragma unroll
        for (int r = 0; r < 4; ++r) {
          av[r].x += __shfl_xor(av[r].x,1); av[r].x += __shfl_xor(av[r].x,2);
          av[r].y += __shfl_xor(av[r].y,1); av[r].y += __shfl_xor(av[r].y,2);
          av[r].z += __shfl_xor(av[r].z,1); av[r].z += __shfl_xor(av[r].z,2);
          av[r].w += __shfl_xor(av[r].w,1); av[r].w += __shfl_xor(av[r].w,2);
        }
        if (sg == 0) {
          float* dst = half ? bw : fw;
#pragma unroll
          for (int r = 0; r < 4; ++r) {
            dst[r*128 + i0+0] = av[r].x; dst[r*128 + i0+1] = av[r].y;
            dst[r*128 + i0+2] = av[r].z; dst[r*128 + i0+3] = av[r].w;
          }
        }
      } else if (tid < 384) {
        int n = tid - 256;
        prc[n] = (1.f - msc[0])*prc[n] + ww[n];
      } else if (tid >= 512) {
        int r = (tid >> 7) & 3, n = tid & 127;
        float dot = 0.f;
#pragma unroll
        for (int w = 0; w < 64; w += 2) {
          float2 m2 = *(float2*)&Ms[n*MST+w];
          float2 k2 = *(float2*)&v[r*64+w];
          dot += m2.x*k2.x + m2.y*k2.y;
        }
        float beta = 1.f + sp_(v[256+r]);
        cr[r*128+n] = beta * dot / ((Mn[n]+EPSF)*(msc[1+r]+EPSF));
      }
      __syncthreads();
      // J'
      if (tid < 256) {
        int r = tid >> 6, l = tid & 63;
        float s1 = cr[r*128+l], s2 = cr[r*128+l+64];
        float m = fmaxf(s1, s2);
#pragma unroll
        for (int o = 32; o > 0; o >>= 1) m = fmaxf(m, __shfl_xor(m, o));
        float e1 = expf(s1-m), e2 = expf(s2-m);
        float dn = e1 + e2;
#pragma unroll
        for (int o = 32; o > 0; o >>= 1) dn += __shfl_xor(dn, o);
        float m0 = msc[8+r*3], m1 = msc[8+r*3+1], m2 = msc[8+r*3+2];
        wr[r*128+l]    = m0*bw[r*128+l]    + m1*(e1/dn) + m2*fw[r*128+l];
        wr[r*128+l+64] = m0*bw[r*128+l+64] + m1*(e2/dn) + m2*fw[r*128+l+64];
      }
      __syncthreads();
      // L: reads publish
      if (tid < 512) {
        int r = tid >> 7, t2 = tid & 127;
        int w0 = (t2 >> 3) * 4, ns = t2 & 7;
        float4 a = {0,0,0,0};
#pragma unroll
        for (int m = 0; m < 16; ++m) {
          int n = ns + m*8;
          float2 ma = *(float2*)&Ms[n*MST + w0];
          float2 mb = *(float2*)&Ms[n*MST + w0 + 2];
          float wv = wr[r*128 + n];
          a.x += wv*ma.x; a.y += wv*ma.y; a.z += wv*mb.x; a.w += wv*mb.y;
        }
        a.x += __shfl_xor(a.x,1); a.x += __shfl_xor(a.x,2); a.x += __shfl_xor(a.x,4);
        a.y += __shfl_xor(a.y,1); a.y += __shfl_xor(a.y,2); a.y += __shfl_xor(a.y,4);
        a.z += __shfl_xor(a.z,1); a.z += __shfl_xor(a.z,2); a.z += __shfl_xor(a.z,4);
        a.w += __shfl_xor(a.w,1); a.w += __shfl_xor(a.w,2); a.w += __shfl_xor(a.w,4);
        if (ns == 0) {
          int o = r*64 + w0;
          float2 lo = {a.x, a.y}, hi = {a.z, a.w};
          st2(&Uh[(size_t)t*UHT + eg*768 + o], lo);
          st2(&Uh[(size_t)t*UHT + eg*768 + o + 2], hi);
        }
      }
      arrive(&FRg[role*FSP], t+1);   // reads(t) published
    }
  } else {
    // ======== COL BLOCK c: h-dims [d0,d1) x 4 gate quadrants + v-cols [v0,v1) ====
    const int c = role - 4;                       // 0..27
    const int egB = g*4;                          // group's first example
    const int d0 = (512*c)/28, d1 = (512*(c+1))/28, Dd = d1-d0, NJ = 4*Dd;
    const int v0 = (471*c)/28, v1 = (471*(c+1))/28, JV = v1-v0;
    unsigned* Wzu = (unsigned*)sm;                // [76][390]
    unsigned* Wiu = (unsigned*)sm + CWI_U;        // [17][262]
    float* us  = sm + CUS_F;                      // [4][772]  16B-aligned base
    float* zh  = sm + CZH_F;                      // [4][76]
    float* cst = sm + CCS_F;                      // [76]

    // ---- one-time: pack weights to bf16 pairs in LDS
    for (int idx = tid; idx < NJ*384; idx += 1024) {
      int j = idx/384, p = idx - j*384, k = 2*p;
      int q = j/Dd, di = j - q*Dd, gc = q*512 + d0 + di;
      float w0 = (k < 256) ? Wx[(size_t)(512+k)*ZD + gc] : Wh[(size_t)(k-256)*ZD + gc];
      float w1 = (k+1 < 256) ? Wx[(size_t)(513+k)*ZD + gc] : Wh[(size_t)(k-255)*ZD + gc];
      Wzu[j*390 + p] = bf16rne(w0) | (bf16rne(w1) << 16);
    }
    for (int idx = tid; idx < JV*256; idx += 1024) {
      int j = idx/256, p = idx - j*256, k = 2*p, gc = v0 + j;
      float w0 = Wif[(size_t)k*IFC + gc];
      float w1 = Wif[(size_t)(k+1)*IFC + gc];
      Wiu[j*262 + p] = bf16rne(w0) | (bf16rne(w1) << 16);
    }
    if (tid < 76) cst[tid] = 0.f;
    // bootstrap z(0) = Xproj(0)
    if (tid < 4*NJ) {
      int e = tid/NJ, j = tid - e*NJ;
      int q = j/Dd, di = j - q*Dd, gc = q*512 + d0 + di;
      zh[e*76 + j] = Xproj[((size_t)(egB+e)*TT + 0)*ZD + gc];
    }
    __syncthreads();
    if (tid < 4*Dd) {
      int e = tid/Dd, di = tid - e*Dd;
      float zi = zh[e*76 + di], zg = zh[e*76 + 2*Dd + di], zo = zh[e*76 + 3*Dd + di];
      float cn = sig_(zi)*tanhf(zg);
      float hn = sig_(zo)*tanhf(cn);
      cst[tid] = cn;
      st1(&Uh[(size_t)0*UHT + (egB + e)*768 + 256 + d0 + di], hn);
    }
    arrive(&FHg[c*FSP], 1);   // h(0) published

    for (int t = 0; t < TT; ++t) {
      // prefetch Xproj(t+1) into registers BEFORE the wait (hides HBM latency)
      float xpre = 0.f; int pe = 0, pj = 0;
      if (t+1 < TT && tid < 4*NJ) {
        pe = tid/NJ; pj = tid - pe*NJ;
        int q = pj/Dd, di = pj - q*Dd, gc = q*512 + d0 + di;
        xpre = Xproj[((size_t)(egB+pe)*TT + t+1)*ZD + gc];
      }
      wait_ge(FHg, 28, t+1);   // h(t) complete (group-local)
      // stage h(t): fresh per-t region, plain cached float4 (16B-aligned dest)
      if (tid < 512) {
        int e = tid >> 7, f4 = (tid & 127) * 4;
        *(float4*)&us[e*772 + 256 + f4] =
            *(const float4*)&Uh[(size_t)t*UHT + (egB+e)*768 + 256 + f4];
      }
      // zh(t+1) init from prefetched Xproj
      if (t+1 < TT && tid < 4*NJ) {
        zh[pe*76 + pj] = xpre;
      }
      __syncthreads();
      // v-gemm: 4e x JV cols, K=512, 8-way k-split, b64 weights + b128 activations
      if (tid < 544) {
        int g8 = tid >> 3, ks = tid & 7;
        int e = g8/17, j = g8 - e*17;
        if (j < JV) {
          float acc = 0.f;
#pragma unroll 4
          for (int m = 0; m < 16; ++m) {
            int p = m*16 + ks*2;
            float4 hv = *(const float4*)&us[e*772 + 256 + 2*p];
            uint2 wu = *(const uint2*)&Wiu[j*262 + p];
            acc += hv.x*bflo(wu.x) + hv.y*bfhi(wu.x)
                 + hv.z*bflo(wu.y) + hv.w*bfhi(wu.y);
          }
          acc += __shfl_xor(acc,1); acc += __shfl_xor(acc,2); acc += __shfl_xor(acc,4);
          if (ks == 0) {
            int col = v0 + j;
            st1(&Vh[(size_t)t*VHT + (egB+e)*480 + col], bif[col] + acc);
          }
        }
      }
      arrive(&FVg[c*FSP], t+1);   // v(t) published
      if (t+1 < TT) {
        // zh += h(t) @ Wh-part (K=512) — overlaps state chain; b64 weights
        if (tid < 608) {
          int q2 = tid >> 1, ks = tid & 1;
          int e = q2/76, j = q2 - e*76;
          if (j < NJ) {
            float acc = 0.f;
#pragma unroll 4
            for (int m = 0; m < 64; ++m) {
              int p = 128 + m*4 + ks*2;
              float4 hv = *(const float4*)&us[e*772 + 2*p];   // 2p>=256 -> h region
              uint2 wu = *(const uint2*)&Wzu[j*390 + p];
              acc += hv.x*bflo(wu.x) + hv.y*bfhi(wu.x)
                   + hv.z*bflo(wu.y) + hv.w*bfhi(wu.y);
            }
            acc += __shfl_xor(acc,1);
            if (ks == 0) zh[e*76 + j] += acc;
          }
        }
        wait_ge(FRg, 4, t+1);   // reads(t) from the group's 4 state blocks
        if (tid < 256) {
          int e = tid >> 6, f4 = (tid & 63) * 4;
          *(float4*)&us[e*772 + f4] =
              *(const float4*)&Uh[(size_t)t*UHT + (egB+e)*768 + f4];
        }
        __syncthreads();
        // z += reads(t) @ WxR-part (K=256) — b64 weights + b128 activations
        if (tid < 608) {
          int q2 = tid >> 1, ks = tid & 1;
          int e = q2/76, j = q2 - e*76;
          if (j < NJ) {
            float acc = 0.f;
#pragma unroll 4
            for (int m = 0; m < 32; ++m) {
              int p = m*4 + ks*2;
              float4 rv = *(const float4*)&us[e*772 + 2*p];
              uint2 wu = *(const uint2*)&Wzu[j*390 + p];
              acc += rv.x*bflo(wu.x) + rv.y*bfhi(wu.x)
                   + rv.z*bflo(wu.y) + rv.w*bfhi(wu.y);
            }
            acc += __shfl_xor(acc,1);
            if (ks == 0) zh[e*76 + j] += acc;
          }
        }
        __syncthreads();
        // gates -> h(t+1), publish
        if (tid < 4*Dd) {
          int e = tid/Dd, di = tid - e*Dd;
          float zi = zh[e*76 + di],      zf = zh[e*76 + Dd + di];
          float zg = zh[e*76 + 2*Dd+di], zo = zh[e*76 + 3*Dd + di];
          float cn = sig_(zf)*cst[tid] + sig_(zi)*tanhf(zg);
          float hn = sig_(zo)*tanhf(cn);
          cst[tid] = cn;
          st1(&Uh[(size_t)(t+1)*UHT + (egB+e)*768 + 256 + d0 + di], hn);
        }
        arrive(&FHg[c*FSP], t+2);   // h(t+1) published
      }
    }
  }
}

extern "C" void kernel_launch(void* const* d_in, const int* in_sizes, int n_in,
                              void* d_out, int out_size, void* d_ws, size_t ws_size,
                              hipStream_t stream) {
  const float* x   = (const float*)d_in[0];
  const float* Wx  = (const float*)d_in[1];
  const float* Wh  = (const float*)d_in[2];
  const float* bl  = (const float*)d_in[3];
  const float* Wif = (const float*)d_in[4];
  const float* bif = (const float*)d_in[5];
  const float* Wo  = (const float*)d_in[6];
  const float* bo  = (const float*)d_in[7];
  float* out = (float*)d_out;

  unsigned* fl = (unsigned*)d_ws;                   // 8192 uints = 32KB (cacheline-spaced flags)
  float* Xp = (float*)(fl + NFLAGS);                // 4096*2048
  float* Uh = Xp + (size_t)4096*2048;               // 128*UHT
  float* Vh = Uh + (size_t)TT*UHT;                  // 128*VHT

  // 1) Xproj = x @ Wx[:512] + b_lstm
  gemm_bias<<<dim3(2048/64, 4096/64), dim3(256), 0, stream>>>(x, Wx, bl, Xp, 2048, 512);

  // 2) flags
  init_flags<<<dim3(8), dim3(1024), 0, stream>>>(fl);

  // 3) XCD-sharded cooperative core: 8 groups x (4 state + 28 col) blocks
  const int smem_bytes = CTOT_F * 4;  // 150256
  (void)hipFuncSetAttribute((const void*)dnc_coop, hipFuncAttributeMaxDynamicSharedMemorySize, smem_bytes);
  void* args[] = { (void*)&Xp, (void*)&Wx, (void*)&Wh, (void*)&Wif, (void*)&bif,
                   (void*)&Uh, (void*)&Vh, (void*)&fl };
  (void)hipLaunchCooperativeKernel((void*)dnc_coop, dim3(NBLK), dim3(1024), args,
                                   (unsigned int)smem_bytes, stream);

  // 4) out = [reads,h] @ W_out + b_out
  gemm_out<<<dim3(512/64, 4096/64), dim3(256), 0, stream>>>(Uh, Wo, bo, out);
}